// Round 10
// baseline (310.392 us; speedup 1.0000x reference)
//
#include <hip/hip_runtime.h>
#include <stdint.h>

#pragma clang fp contract(off)

#define NB 16
#define NC 80
#define P_TOT 17064
#define P4 (P_TOT / 4)
#define PRE_K 1000
#define POST_K 100

__device__ __forceinline__ float sigmoidf_(float x) {
  return 1.0f / (1.0f + expf(-x));
}

// Fast zero of ghist (4 MB) — full-grid, ~2us.
__global__ __launch_bounds__(256) void zero_kernel(uint4* __restrict__ p, int n4) {
  int i = blockIdx.x * 256 + threadIdx.x;
  if (i < n4) p[i] = make_uint4(0u, 0u, 0u, 0u);
}

// Decode (monotonicity trick: argmax over classes == argmax over raw logits;
// exact score computed once for the winner) + FUSED histogram of key top-16.
__global__ __launch_bounds__(256) void decode_kernel(
    const float* __restrict__ cls0, const float* __restrict__ reg0, const float* __restrict__ ctr0,
    const float* __restrict__ cls1, const float* __restrict__ reg1, const float* __restrict__ ctr1,
    const float* __restrict__ cls2, const float* __restrict__ reg2, const float* __restrict__ ctr2,
    const float* __restrict__ cls3, const float* __restrict__ reg3, const float* __restrict__ ctr3,
    const float* __restrict__ cls4, const float* __restrict__ reg4, const float* __restrict__ ctr4,
    int* __restrict__ labels, float* __restrict__ boxes,
    unsigned long long* __restrict__ keys, unsigned* __restrict__ ghist)
{
  int quad = blockIdx.x * 64 + (threadIdx.x >> 2);
  int t4 = threadIdx.x & 3;
  int n = blockIdx.y;
  if (quad >= P4) return;
  int p0 = quad * 4;
  int off, wsh, hw; float stride; const float *cls, *reg, *ctr;
  if (p0 < 12800)      { off = 0;     wsh = 7; hw = 12800; stride = 8.f;   cls = cls0; reg = reg0; ctr = ctr0; }
  else if (p0 < 16000) { off = 12800; wsh = 6; hw = 3200;  stride = 16.f;  cls = cls1; reg = reg1; ctr = ctr1; }
  else if (p0 < 16800) { off = 16000; wsh = 5; hw = 800;   stride = 32.f;  cls = cls2; reg = reg2; ctr = ctr2; }
  else if (p0 < 17008) { off = 16800; wsh = 4; hw = 208;   stride = 64.f;  cls = cls3; reg = reg3; ctr = ctr3; }
  else                 { off = 17008; wsh = 3; hw = 56;    stride = 128.f; cls = cls4; reg = reg4; ctr = ctr4; }
  int loc0 = p0 - off;
  int y = loc0 >> wsh;
  int x0 = loc0 & ((1 << wsh) - 1);
  float py = (float)y * stride + 0.5f * stride;

  int c0 = t4 * 20;
  const float* cptr = cls + (size_t)n * NC * hw + (size_t)c0 * hw + loc0;
  float best[4] = { -3.4e38f, -3.4e38f, -3.4e38f, -3.4e38f };
  int bl[4] = { c0, c0, c0, c0 };
  #pragma unroll
  for (int k = 0; k < 20; ++k) {
    float4 cv = *reinterpret_cast<const float4*>(cptr + (size_t)k * hw);
    int c = c0 + k;
    if (cv.x > best[0]) { best[0] = cv.x; bl[0] = c; }
    if (cv.y > best[1]) { best[1] = cv.y; bl[1] = c; }
    if (cv.z > best[2]) { best[2] = cv.z; bl[2] = c; }
    if (cv.w > best[3]) { best[3] = cv.w; bl[3] = c; }
  }
  #pragma unroll
  for (int e = 0; e < 4; ++e) {
    #pragma unroll
    for (int d = 1; d <= 2; d <<= 1) {
      float ob = __shfl_xor(best[e], d);
      int ol = __shfl_xor(bl[e], d);
      if (ob > best[e] || (ob == best[e] && ol < bl[e])) { best[e] = ob; bl[e] = ol; }
    }
  }
  if (t4 != 0) return;

  float4 c4 = *reinterpret_cast<const float4*>(ctr + (size_t)n * hw + loc0);
  float sctr[4] = { sigmoidf_(c4.x), sigmoidf_(c4.y), sigmoidf_(c4.z), sigmoidf_(c4.w) };

  const float* rbase = reg + (size_t)n * 4 * hw + loc0;
  float4 rl = *reinterpret_cast<const float4*>(rbase);
  float4 rt = *reinterpret_cast<const float4*>(rbase + (size_t)hw);
  float4 rr = *reinterpret_cast<const float4*>(rbase + (size_t)2 * hw);
  float4 rb = *reinterpret_cast<const float4*>(rbase + (size_t)3 * hw);
  float dl[4] = { rl.x, rl.y, rl.z, rl.w };
  float dt[4] = { rt.x, rt.y, rt.z, rt.w };
  float dr[4] = { rr.x, rr.y, rr.z, rr.w };
  float db[4] = { rb.x, rb.y, rb.z, rb.w };

  size_t o0 = (size_t)n * P_TOT + p0;
  int4 bl4; int* blp = &bl4.x;
  unsigned long long kk[4];
  #pragma unroll
  for (int e = 0; e < 4; ++e) {
    float s = sqrtf(sigmoidf_(best[e]) * sctr[e]);
    float val = (s > 0.05f) ? s : 0.0f;
    float px = (float)(x0 + e) * stride + 0.5f * stride;
    float x1 = fminf(fmaxf(px - dl[e], 0.f), 1024.f);
    float y1 = fminf(fmaxf(py - dt[e], 0.f), 800.f);
    float x2 = fminf(fmaxf(px + dr[e], 0.f), 1024.f);
    float y2 = fminf(fmaxf(py + db[e], 0.f), 800.f);
    blp[e] = bl[e];
    *reinterpret_cast<float4*>(boxes + 4 * (o0 + e)) = make_float4(x1, y1, x2, y2);
    kk[e] = ((unsigned long long)__float_as_uint(val) << 32)
          | (unsigned long long)(0xFFFFFFFFu - (unsigned)(p0 + e));
  }
  *reinterpret_cast<int4*>(labels + o0) = bl4;
  ulonglong2 k01; k01.x = kk[0]; k01.y = kk[1];
  ulonglong2 k23; k23.x = kk[2]; k23.y = kk[3];
  *reinterpret_cast<ulonglong2*>(keys + o0) = k01;
  *reinterpret_cast<ulonglong2*>(keys + o0 + 2) = k23;
  // fused histogram
  unsigned* gh = ghist + ((size_t)n << 16);
  #pragma unroll
  for (int e = 0; e < 4; ++e) atomicAdd(&gh[(unsigned)(kk[e] >> 48)], 1u);
}

// Phase B: threshold digit + per-bin base offsets + zero staging.
__global__ __launch_bounds__(1024) void selB_kernel(
    unsigned* __restrict__ ghist, unsigned* __restrict__ dsel_arr,
    unsigned long long* __restrict__ stage)
{
  int n = blockIdx.x;
  int tid = threadIdx.x;
  __shared__ unsigned A[1024];
  __shared__ unsigned s_d;

  unsigned* gh = ghist + ((size_t)n << 16);
  unsigned bvs[64];
  const uint4* gh4 = reinterpret_cast<const uint4*>(gh) + (size_t)tid * 16;
  unsigned ssum = 0;
  #pragma unroll
  for (int q = 0; q < 16; ++q) {
    uint4 v = gh4[q];
    bvs[4*q+0] = v.x; bvs[4*q+1] = v.y; bvs[4*q+2] = v.z; bvs[4*q+3] = v.w;
    ssum += v.x + v.y + v.z + v.w;
  }
  A[tid] = ssum;
  __syncthreads();
  for (int ofs = 1; ofs < 1024; ofs <<= 1) {
    unsigned v = A[tid];
    if (tid + ofs < 1024) v += A[tid + ofs];
    __syncthreads();
    A[tid] = v;
    __syncthreads();
  }
  unsigned An = (tid < 1023) ? A[tid + 1] : 0u;
  {
    unsigned At = A[tid];
    if (At >= PRE_K && An < PRE_K) {
      unsigned cum = An;
      int d = tid * 64;
      bool done = false;
      #pragma unroll
      for (int b = 63; b >= 0; --b) {
        if (!done) {
          cum += bvs[b];
          if (cum >= PRE_K) { d = tid * 64 + b; done = true; }
        }
      }
      s_d = (unsigned)d;
      dsel_arr[n] = (unsigned)d;
    }
  }
  __syncthreads();
  unsigned dsel = s_d;
  {
    unsigned cum = An;
    #pragma unroll
    for (int b = 63; b >= 0; --b) {
      unsigned h = (unsigned)(tid * 64 + b);
      if (h >= dsel && bvs[b] != 0u) gh[h] = cum;
      cum += bvs[b];
    }
  }
  stage[(size_t)n * 2048 + tid] = 0ULL;
  stage[(size_t)n * 2048 + tid + 1024] = 0ULL;
}

// Phase C: parallel bucket scatter into 2048-slot staging.
__global__ __launch_bounds__(256) void scatter_kernel(
    const unsigned long long* __restrict__ keys, unsigned* __restrict__ ghist,
    const unsigned* __restrict__ dsel_arr, unsigned long long* __restrict__ stage)
{
  int p = blockIdx.x * 256 + threadIdx.x;
  int n = blockIdx.y;
  if (p >= P_TOT) return;
  unsigned long long k = keys[(size_t)n * P_TOT + p];
  unsigned h = (unsigned)(k >> 48);
  if (h < dsel_arr[n]) return;
  unsigned old = atomicAdd(&ghist[((size_t)n << 16) + h], 0x10000u);
  unsigned slot = (old & 0xFFFFu) + (old >> 16);
  if (slot < 2048) stage[(size_t)n * 2048 + slot] = k;
}

// Phase D: bitonic sort 2048 desc + FUSED gather of boxes/labels/scores.
__global__ __launch_bounds__(1024) void sortG_kernel(
    const unsigned long long* __restrict__ stage,
    const float* __restrict__ boxes, const int* __restrict__ labels,
    float* __restrict__ tboxes, float* __restrict__ tscores, int* __restrict__ tlabels)
{
  int n = blockIdx.x;
  int tid = threadIdx.x;
  __shared__ unsigned long long skey[2048];
  skey[tid] = stage[(size_t)n * 2048 + tid];
  skey[tid + 1024] = stage[(size_t)n * 2048 + tid + 1024];
  __syncthreads();
  for (int k2 = 2; k2 <= 2048; k2 <<= 1) {
    for (int j = k2 >> 1; j > 0; j >>= 1) {
      #pragma unroll
      for (int e = 0; e < 2; ++e) {
        int idx = tid + e * 1024;
        int ixj = idx ^ j;
        if (ixj > idx) {
          unsigned long long a = skey[idx], bb = skey[ixj];
          bool sw = ((idx & k2) == 0) ? (a < bb) : (a > bb);
          if (sw) { skey[idx] = bb; skey[ixj] = a; }
        }
      }
      __syncthreads();
    }
  }
  if (tid < PRE_K) {
    unsigned long long k = skey[tid];
    unsigned idx = 0xFFFFFFFFu - (unsigned)(k & 0xFFFFFFFFu);
    float sc = __uint_as_float((unsigned)(k >> 32));
    size_t src = (size_t)n * P_TOT + idx;
    size_t dst = (size_t)n * PRE_K + tid;
    tscores[dst] = sc;
    tlabels[dst] = labels[src];
    *reinterpret_cast<float4*>(tboxes + 4 * dst) =
        *reinterpret_cast<const float4*>(boxes + 4 * src);
  }
}

// Fused NMS: per batch, one 1024-thread block.
// Per 64-chunk c: (A) 1024 thr compute the 64x64 diag suppression bits
// (4 IoUs each, LDS atomicOr into colmask), (B) wave 0 runs the ballot
// fixpoint (== sequential greedy), (C) all threads suppress LATER columns
// against this chunk's kept rows only. Then in-block finalize + output.
// IoU arithmetic identical to reference (offset boxes, precise divide).
__global__ __launch_bounds__(1024) void nms_kernel(
    const float* __restrict__ tboxes, const float* __restrict__ tscores,
    const int* __restrict__ tlabels, float* __restrict__ out)
{
  int n = blockIdx.x;
  int tid = threadIdx.x;
  int wave = tid >> 6;
  int lane = tid & 63;

  __shared__ float4 Boff[1024];
  __shared__ float4 Borig[1024];
  __shared__ float Ar[1024];
  __shared__ float Sc[1024];
  __shared__ int Lb[1024];
  __shared__ unsigned long long colmask[64];
  __shared__ unsigned long long keptw[16];
  __shared__ unsigned long long remw[16];
  __shared__ unsigned long long spos[16];

  {
    float4 b = make_float4(0.f, 0.f, 0.f, 0.f);
    float s = 0.f; int lb = 0;
    if (tid < PRE_K) {
      size_t src = (size_t)n * PRE_K + tid;
      b = *reinterpret_cast<const float4*>(tboxes + 4 * src);
      s = tscores[src];
      lb = tlabels[src];
    }
    float offv = (float)lb * 4096.0f;
    float4 bo = make_float4(b.x + offv, b.y + offv, b.z + offv, b.w + offv);
    Borig[tid] = b;
    Boff[tid] = bo;
    Ar[tid] = (bo.z - bo.x) * (bo.w - bo.y);
    Sc[tid] = s;
    Lb[tid] = lb;
    unsigned long long sp = __ballot(s > 0.f);
    if (lane == 0) { spos[wave] = sp; remw[wave] = 0ULL; keptw[wave] = 0ULL; }
  }
  __syncthreads();

  for (int c = 0; c < 16; ++c) {
    if (tid < 64) colmask[tid] = 0ULL;
    __syncthreads();
    // (A) diag 64x64: thread -> column (tid&63), rows (tid>>6)*4 .. +3
    {
      int col = tid & 63;
      int r0 = (tid >> 6) * 4;
      int jj = c * 64 + col;
      float4 bj = Boff[jj];
      float aj = Ar[jj];
      unsigned long long partial = 0ULL;
      #pragma unroll
      for (int q = 0; q < 4; ++q) {
        int r = r0 + q;
        if (r < col) {
          int ii = c * 64 + r;
          float4 bi = Boff[ii];
          float ai = Ar[ii];
          float lx = fmaxf(bi.x, bj.x), ly = fmaxf(bi.y, bj.y);
          float rx = fminf(bi.z, bj.z), ry = fminf(bi.w, bj.w);
          float iw = fmaxf(rx - lx, 0.f), ih = fmaxf(ry - ly, 0.f);
          float inter = iw * ih;
          float iou = inter / (ai + aj - inter + 1e-9f);
          if (iou > 0.6f) partial |= (1ull << r);
        }
      }
      if (partial) atomicOr(&colmask[col], partial);
    }
    __syncthreads();
    // (B) fixpoint greedy on wave 0
    if (wave == 0) {
      unsigned long long col_l = colmask[lane];
      unsigned long long K = spos[c] & ~remw[c];
      unsigned long long kept = 0ULL;
      for (int it = 0; it < 64; ++it) {
        unsigned long long Bsupp = __ballot((col_l & K) != 0ULL);
        unsigned long long Snew = K & ~Bsupp & ~kept;
        if (Snew == 0ULL) break;
        kept |= Snew;
        unsigned long long Bd = __ballot((col_l & kept) != 0ULL);
        K &= ~Bd;
      }
      unsigned long long newrem = __ballot((col_l & kept) != 0ULL);
      if (lane == 0) { keptw[c] = kept; remw[c] |= newrem; }
    }
    __syncthreads();
    // (C) suppress later columns vs kept rows of chunk c
    if (c < 15) {
      int jj = (c + 1) * 64 + tid;
      bool suppd = false;
      if (jj < PRE_K) {
        int widx = (jj >> 6);
        bool already = (remw[widx] >> (jj & 63)) & 1ull;
        if (!already) {
          unsigned long long kb = keptw[c];
          float4 bj = Boff[jj];
          float aj = Ar[jj];
          while (kb) {
            int b = __ffsll(kb) - 1; kb &= kb - 1;
            int ii = c * 64 + b;
            float4 bi = Boff[ii];
            float ai = Ar[ii];
            float lx = fmaxf(bi.x, bj.x), ly = fmaxf(bi.y, bj.y);
            float rx = fminf(bi.z, bj.z), ry = fminf(bi.w, bj.w);
            float iw = fmaxf(rx - lx, 0.f), ih = fmaxf(ry - ly, 0.f);
            float inter = iw * ih;
            float iou = inter / (ai + aj - inter + 1e-9f);
            if (iou > 0.6f) { suppd = true; break; }
          }
        }
      }
      unsigned long long bmask = __ballot(suppd);
      int widx = c + 1 + wave;
      if (lane == 0 && bmask && widx < 16) remw[widx] |= bmask;
    }
    __syncthreads();
  }

  // finalize: keep = bit tid of keptw; zero-score fill preserves index order
  __shared__ unsigned sk[1024];
  __shared__ unsigned sz[1024];
  bool inr = (tid < PRE_K);
  bool keep = inr && (((keptw[tid >> 6] >> (tid & 63)) & 1ull) != 0ull);
  sk[tid] = keep ? 1u : 0u;
  sz[tid] = (inr && !keep) ? 1u : 0u;
  __syncthreads();
  for (int ofs = 1; ofs < 1024; ofs <<= 1) {
    unsigned a = (tid >= ofs) ? sk[tid - ofs] : 0;
    unsigned b = (tid >= ofs) ? sz[tid - ofs] : 0;
    __syncthreads();
    sk[tid] += a; sz[tid] += b;
    __syncthreads();
  }
  int nk = (int)sk[1023];
  int slot = -1;
  if (inr) {
    if (keep) {
      int r = (int)sk[tid] - 1;
      if (r < POST_K) slot = r;
    } else {
      int r = nk + (int)sz[tid] - 1;
      if (r < POST_K) slot = r;
    }
  }
  if (slot >= 0) {
    size_t ob = ((size_t)n * POST_K + slot) * 4;
    float4 b = Borig[tid];
    out[ob+0] = b.x; out[ob+1] = b.y; out[ob+2] = b.z; out[ob+3] = b.w;
    out[(size_t)NB*POST_K*4 + (size_t)n*POST_K + slot] = keep ? Sc[tid] : 0.0f;
    out[(size_t)NB*POST_K*5 + (size_t)n*POST_K + slot] = (float)Lb[tid];
  }
}

extern "C" void kernel_launch(void* const* d_in, const int* in_sizes, int n_in,
                              void* d_out, int out_size, void* d_ws, size_t ws_size,
                              hipStream_t stream) {
  char* w = (char*)d_ws;
  auto carve = [&](size_t bytes) { char* p = w; w += (bytes + 255) & ~(size_t)255; return p; };
  int* labels   = (int*)carve((size_t)NB * P_TOT * 4);
  float* boxes  = (float*)carve((size_t)NB * P_TOT * 16);
  unsigned long long* keys    = (unsigned long long*)carve((size_t)NB * P_TOT * 8);
  unsigned* ghist = (unsigned*)carve((size_t)NB * 65536 * 4);
  unsigned* dsel_arr = (unsigned*)carve(NB * 4);
  unsigned long long* stage = (unsigned long long*)carve((size_t)NB * 2048 * 8);
  float* tboxes  = (float*)carve((size_t)NB * PRE_K * 16);
  float* tscores = (float*)carve((size_t)NB * PRE_K * 4);
  int* tlabels   = (int*)carve((size_t)NB * PRE_K * 4);

  const float* cls0 = (const float*)d_in[0];
  const float* reg0 = (const float*)d_in[1];
  const float* ctr0 = (const float*)d_in[2];
  const float* cls1 = (const float*)d_in[3];
  const float* reg1 = (const float*)d_in[4];
  const float* ctr1 = (const float*)d_in[5];
  const float* cls2 = (const float*)d_in[6];
  const float* reg2 = (const float*)d_in[7];
  const float* ctr2 = (const float*)d_in[8];
  const float* cls3 = (const float*)d_in[9];
  const float* reg3 = (const float*)d_in[10];
  const float* ctr3 = (const float*)d_in[11];
  const float* cls4 = (const float*)d_in[12];
  const float* reg4 = (const float*)d_in[13];
  const float* ctr4 = (const float*)d_in[14];

  int n4 = NB * 65536 / 4;
  zero_kernel<<<(n4 + 255) / 256, 256, 0, stream>>>((uint4*)ghist, n4);
  dim3 dg((P4 + 63) / 64, NB);
  decode_kernel<<<dg, 256, 0, stream>>>(cls0, reg0, ctr0, cls1, reg1, ctr1,
                                        cls2, reg2, ctr2, cls3, reg3, ctr3,
                                        cls4, reg4, ctr4,
                                        labels, boxes, keys, ghist);
  selB_kernel<<<NB, 1024, 0, stream>>>(ghist, dsel_arr, stage);
  dim3 gh((P_TOT + 255) / 256, NB);
  scatter_kernel<<<gh, 256, 0, stream>>>(keys, ghist, dsel_arr, stage);
  sortG_kernel<<<NB, 1024, 0, stream>>>(stage, boxes, labels, tboxes, tscores, tlabels);
  nms_kernel<<<NB, 1024, 0, stream>>>(tboxes, tscores, tlabels, (float*)d_out);
}

// Round 11
// 143.978 us; speedup vs baseline: 2.1558x; 2.1558x over previous
//
#include <hip/hip_runtime.h>
#include <stdint.h>

#pragma clang fp contract(off)

#define NB 16
#define NC 80
#define P_TOT 17064
#define P4 (P_TOT / 4)
#define PRE_K 1000
#define POST_K 100

__device__ __forceinline__ float sigmoidf_(float x) {
  return 1.0f / (1.0f + expf(-x));
}

// Fast zero of ghist (4 MB) — full-grid, ~2us.
__global__ __launch_bounds__(256) void zero_kernel(uint4* __restrict__ p, int n4) {
  int i = blockIdx.x * 256 + threadIdx.x;
  if (i < n4) p[i] = make_uint4(0u, 0u, 0u, 0u);
}

// Decode (monotonicity trick: argmax over classes == argmax over raw logits;
// exact score computed once for the winner) + FUSED histogram of key top-16.
__global__ __launch_bounds__(256) void decode_kernel(
    const float* __restrict__ cls0, const float* __restrict__ reg0, const float* __restrict__ ctr0,
    const float* __restrict__ cls1, const float* __restrict__ reg1, const float* __restrict__ ctr1,
    const float* __restrict__ cls2, const float* __restrict__ reg2, const float* __restrict__ ctr2,
    const float* __restrict__ cls3, const float* __restrict__ reg3, const float* __restrict__ ctr3,
    const float* __restrict__ cls4, const float* __restrict__ reg4, const float* __restrict__ ctr4,
    int* __restrict__ labels, float* __restrict__ boxes,
    unsigned long long* __restrict__ keys, unsigned* __restrict__ ghist)
{
  int quad = blockIdx.x * 64 + (threadIdx.x >> 2);
  int t4 = threadIdx.x & 3;
  int n = blockIdx.y;
  if (quad >= P4) return;
  int p0 = quad * 4;
  int off, wsh, hw; float stride; const float *cls, *reg, *ctr;
  if (p0 < 12800)      { off = 0;     wsh = 7; hw = 12800; stride = 8.f;   cls = cls0; reg = reg0; ctr = ctr0; }
  else if (p0 < 16000) { off = 12800; wsh = 6; hw = 3200;  stride = 16.f;  cls = cls1; reg = reg1; ctr = ctr1; }
  else if (p0 < 16800) { off = 16000; wsh = 5; hw = 800;   stride = 32.f;  cls = cls2; reg = reg2; ctr = ctr2; }
  else if (p0 < 17008) { off = 16800; wsh = 4; hw = 208;   stride = 64.f;  cls = cls3; reg = reg3; ctr = ctr3; }
  else                 { off = 17008; wsh = 3; hw = 56;    stride = 128.f; cls = cls4; reg = reg4; ctr = ctr4; }
  int loc0 = p0 - off;
  int y = loc0 >> wsh;
  int x0 = loc0 & ((1 << wsh) - 1);
  float py = (float)y * stride + 0.5f * stride;

  int c0 = t4 * 20;
  const float* cptr = cls + (size_t)n * NC * hw + (size_t)c0 * hw + loc0;
  float best[4] = { -3.4e38f, -3.4e38f, -3.4e38f, -3.4e38f };
  int bl[4] = { c0, c0, c0, c0 };
  #pragma unroll
  for (int k = 0; k < 20; ++k) {
    float4 cv = *reinterpret_cast<const float4*>(cptr + (size_t)k * hw);
    int c = c0 + k;
    if (cv.x > best[0]) { best[0] = cv.x; bl[0] = c; }
    if (cv.y > best[1]) { best[1] = cv.y; bl[1] = c; }
    if (cv.z > best[2]) { best[2] = cv.z; bl[2] = c; }
    if (cv.w > best[3]) { best[3] = cv.w; bl[3] = c; }
  }
  #pragma unroll
  for (int e = 0; e < 4; ++e) {
    #pragma unroll
    for (int d = 1; d <= 2; d <<= 1) {
      float ob = __shfl_xor(best[e], d);
      int ol = __shfl_xor(bl[e], d);
      if (ob > best[e] || (ob == best[e] && ol < bl[e])) { best[e] = ob; bl[e] = ol; }
    }
  }
  if (t4 != 0) return;

  float4 c4 = *reinterpret_cast<const float4*>(ctr + (size_t)n * hw + loc0);
  float sctr[4] = { sigmoidf_(c4.x), sigmoidf_(c4.y), sigmoidf_(c4.z), sigmoidf_(c4.w) };

  const float* rbase = reg + (size_t)n * 4 * hw + loc0;
  float4 rl = *reinterpret_cast<const float4*>(rbase);
  float4 rt = *reinterpret_cast<const float4*>(rbase + (size_t)hw);
  float4 rr = *reinterpret_cast<const float4*>(rbase + (size_t)2 * hw);
  float4 rb = *reinterpret_cast<const float4*>(rbase + (size_t)3 * hw);
  float dl[4] = { rl.x, rl.y, rl.z, rl.w };
  float dt[4] = { rt.x, rt.y, rt.z, rt.w };
  float dr[4] = { rr.x, rr.y, rr.z, rr.w };
  float db[4] = { rb.x, rb.y, rb.z, rb.w };

  size_t o0 = (size_t)n * P_TOT + p0;
  int4 bl4; int* blp = &bl4.x;
  unsigned long long kk[4];
  #pragma unroll
  for (int e = 0; e < 4; ++e) {
    float s = sqrtf(sigmoidf_(best[e]) * sctr[e]);
    float val = (s > 0.05f) ? s : 0.0f;
    float px = (float)(x0 + e) * stride + 0.5f * stride;
    float x1 = fminf(fmaxf(px - dl[e], 0.f), 1024.f);
    float y1 = fminf(fmaxf(py - dt[e], 0.f), 800.f);
    float x2 = fminf(fmaxf(px + dr[e], 0.f), 1024.f);
    float y2 = fminf(fmaxf(py + db[e], 0.f), 800.f);
    blp[e] = bl[e];
    *reinterpret_cast<float4*>(boxes + 4 * (o0 + e)) = make_float4(x1, y1, x2, y2);
    kk[e] = ((unsigned long long)__float_as_uint(val) << 32)
          | (unsigned long long)(0xFFFFFFFFu - (unsigned)(p0 + e));
  }
  *reinterpret_cast<int4*>(labels + o0) = bl4;
  ulonglong2 k01; k01.x = kk[0]; k01.y = kk[1];
  ulonglong2 k23; k23.x = kk[2]; k23.y = kk[3];
  *reinterpret_cast<ulonglong2*>(keys + o0) = k01;
  *reinterpret_cast<ulonglong2*>(keys + o0 + 2) = k23;
  // fused histogram
  unsigned* gh = ghist + ((size_t)n << 16);
  #pragma unroll
  for (int e = 0; e < 4; ++e) atomicAdd(&gh[(unsigned)(kk[e] >> 48)], 1u);
}

// Phase B: threshold digit + per-bin base offsets + zero staging.
__global__ __launch_bounds__(1024) void selB_kernel(
    unsigned* __restrict__ ghist, unsigned* __restrict__ dsel_arr,
    unsigned long long* __restrict__ stage)
{
  int n = blockIdx.x;
  int tid = threadIdx.x;
  __shared__ unsigned A[1024];
  __shared__ unsigned s_d;

  unsigned* gh = ghist + ((size_t)n << 16);
  unsigned bvs[64];
  const uint4* gh4 = reinterpret_cast<const uint4*>(gh) + (size_t)tid * 16;
  unsigned ssum = 0;
  #pragma unroll
  for (int q = 0; q < 16; ++q) {
    uint4 v = gh4[q];
    bvs[4*q+0] = v.x; bvs[4*q+1] = v.y; bvs[4*q+2] = v.z; bvs[4*q+3] = v.w;
    ssum += v.x + v.y + v.z + v.w;
  }
  A[tid] = ssum;
  __syncthreads();
  for (int ofs = 1; ofs < 1024; ofs <<= 1) {
    unsigned v = A[tid];
    if (tid + ofs < 1024) v += A[tid + ofs];
    __syncthreads();
    A[tid] = v;
    __syncthreads();
  }
  unsigned An = (tid < 1023) ? A[tid + 1] : 0u;
  {
    unsigned At = A[tid];
    if (At >= PRE_K && An < PRE_K) {
      unsigned cum = An;
      int d = tid * 64;
      bool done = false;
      #pragma unroll
      for (int b = 63; b >= 0; --b) {
        if (!done) {
          cum += bvs[b];
          if (cum >= PRE_K) { d = tid * 64 + b; done = true; }
        }
      }
      s_d = (unsigned)d;
      dsel_arr[n] = (unsigned)d;
    }
  }
  __syncthreads();
  unsigned dsel = s_d;
  {
    unsigned cum = An;
    #pragma unroll
    for (int b = 63; b >= 0; --b) {
      unsigned h = (unsigned)(tid * 64 + b);
      if (h >= dsel && bvs[b] != 0u) gh[h] = cum;
      cum += bvs[b];
    }
  }
  stage[(size_t)n * 2048 + tid] = 0ULL;
  stage[(size_t)n * 2048 + tid + 1024] = 0ULL;
}

// Phase C: parallel bucket scatter into 2048-slot staging.
__global__ __launch_bounds__(256) void scatter_kernel(
    const unsigned long long* __restrict__ keys, unsigned* __restrict__ ghist,
    const unsigned* __restrict__ dsel_arr, unsigned long long* __restrict__ stage)
{
  int p = blockIdx.x * 256 + threadIdx.x;
  int n = blockIdx.y;
  if (p >= P_TOT) return;
  unsigned long long k = keys[(size_t)n * P_TOT + p];
  unsigned h = (unsigned)(k >> 48);
  if (h < dsel_arr[n]) return;
  unsigned old = atomicAdd(&ghist[((size_t)n << 16) + h], 0x10000u);
  unsigned slot = (old & 0xFFFFu) + (old >> 16);
  if (slot < 2048) stage[(size_t)n * 2048 + slot] = k;
}

// Phase D: bitonic sort 2048 desc + FUSED gather of boxes/labels/scores.
__global__ __launch_bounds__(1024) void sortG_kernel(
    const unsigned long long* __restrict__ stage,
    const float* __restrict__ boxes, const int* __restrict__ labels,
    float* __restrict__ tboxes, float* __restrict__ tscores, int* __restrict__ tlabels)
{
  int n = blockIdx.x;
  int tid = threadIdx.x;
  __shared__ unsigned long long skey[2048];
  skey[tid] = stage[(size_t)n * 2048 + tid];
  skey[tid + 1024] = stage[(size_t)n * 2048 + tid + 1024];
  __syncthreads();
  for (int k2 = 2; k2 <= 2048; k2 <<= 1) {
    for (int j = k2 >> 1; j > 0; j >>= 1) {
      #pragma unroll
      for (int e = 0; e < 2; ++e) {
        int idx = tid + e * 1024;
        int ixj = idx ^ j;
        if (ixj > idx) {
          unsigned long long a = skey[idx], bb = skey[ixj];
          bool sw = ((idx & k2) == 0) ? (a < bb) : (a > bb);
          if (sw) { skey[idx] = bb; skey[ixj] = a; }
        }
      }
      __syncthreads();
    }
  }
  if (tid < PRE_K) {
    unsigned long long k = skey[tid];
    unsigned idx = 0xFFFFFFFFu - (unsigned)(k & 0xFFFFFFFFu);
    float sc = __uint_as_float((unsigned)(k >> 32));
    size_t src = (size_t)n * P_TOT + idx;
    size_t dst = (size_t)n * PRE_K + tid;
    tscores[dst] = sc;
    tlabels[dst] = labels[src];
    *reinterpret_cast<float4*>(tboxes + 4 * dst) =
        *reinterpret_cast<const float4*>(boxes + 4 * src);
  }
}

// COLUMN-major suppression on a 2048-block grid (full-chip parallel).
// Thread (jb*128+tid) computes word w of column j. Divide-free guard-band:
// t = inter - 0.6f*denom decides unless |t| <= denom*2^-17, where the exact
// reference divide resolves. Decisions bit-identical to fl(inter/denom)>0.6f.
__global__ __launch_bounds__(128) void iou_kernel(
    const float* __restrict__ tboxes, const int* __restrict__ tlabels,
    unsigned long long* __restrict__ colsupp)
{
  int jb = blockIdx.x, w = blockIdx.y, n = blockIdx.z;
  int tid = threadIdx.x;
  int j = jb * 128 + tid;
  bool jvalid = (j < PRE_K);
  int ibase = w * 64;

  if (ibase >= jb * 128 + 128) {  // entirely above diagonal
    if (jvalid) colsupp[((size_t)n * PRE_K + j) * 16 + w] = 0ULL;
    return;
  }

  __shared__ float4 sb[64];
  __shared__ float sa[64];
  if (tid < 64) {
    int i = ibase + tid;
    float4 v = make_float4(0.f, 0.f, 0.f, 0.f);
    if (i < PRE_K) {
      const float* b = tboxes + ((size_t)n * PRE_K + i) * 4;
      float offv = (float)tlabels[(size_t)n * PRE_K + i] * 4096.0f;
      v = make_float4(b[0] + offv, b[1] + offv, b[2] + offv, b[3] + offv);
    }
    sb[tid] = v;
    sa[tid] = (v.z - v.x) * (v.w - v.y);
  }
  __syncthreads();

  float4 bj = make_float4(0.f, 0.f, 0.f, 0.f);
  if (jvalid) {
    const float* b = tboxes + ((size_t)n * PRE_K + j) * 4;
    float offv = (float)tlabels[(size_t)n * PRE_K + j] * 4096.0f;
    bj = make_float4(b[0] + offv, b[1] + offv, b[2] + offv, b[3] + offv);
  }
  float aj = (bj.z - bj.x) * (bj.w - bj.y);

  unsigned long long m = 0, mb = 0;
  #pragma unroll
  for (int b = 0; b < 64; ++b) {
    float4 bi = sb[b];
    float ai = sa[b];
    float lx = fmaxf(bi.x, bj.x), ly = fmaxf(bi.y, bj.y);
    float rx = fminf(bi.z, bj.z), ry = fminf(bi.w, bj.w);
    float iw = fmaxf(rx - lx, 0.f), ih = fmaxf(ry - ly, 0.f);
    float inter = iw * ih;
    float denom = ai + aj - inter + 1e-9f;
    float t = inter - 0.6f * denom;
    if (t > 0.f) m |= (1ull << b);
    if (fabsf(t) <= denom * 7.62939453125e-6f) mb |= (1ull << b);  // 2^-17
  }
  if (mb) {  // rare: resolve borderline bits with the exact reference divide
    unsigned long long r = mb;
    while (r) {
      int b = __ffsll(r) - 1; r &= r - 1;
      float4 bi = sb[b];
      float ai = sa[b];
      float lx = fmaxf(bi.x, bj.x), ly = fmaxf(bi.y, bj.y);
      float rx = fminf(bi.z, bj.z), ry = fminf(bi.w, bj.w);
      float iw = fmaxf(rx - lx, 0.f), ih = fmaxf(ry - ly, 0.f);
      float inter = iw * ih;
      float denom = ai + aj - inter + 1e-9f;
      float iou = inter / denom;
      if (iou > 0.6f) m |= (1ull << b); else m &= ~(1ull << b);
    }
  }
  unsigned long long tri;
  if (ibase >= j) tri = 0ULL;
  else if (j - ibase >= 64) tri = ~0ULL;
  else tri = (1ull << (j - ibase)) - 1ull;
  m &= tri;
  if (jvalid) colsupp[((size_t)n * PRE_K + j) * 16 + w] = m;
}

// One wave per batch. Fixpoint greedy (provably == sequential greedy scan).
__global__ __launch_bounds__(64, 1) void greedy_kernel(
    const unsigned long long* __restrict__ colsupp, const float* __restrict__ tscores,
    unsigned long long* __restrict__ keepmask)
{
  int n = blockIdx.x;
  int l = threadIdx.x;
  const unsigned long long* C = colsupp + (size_t)n * PRE_K * 16;
  const float* sc = tscores + (size_t)n * PRE_K;

  unsigned long long diag[16];
  float sval[16];
  #pragma unroll
  for (int k = 0; k < 16; ++k) {
    int j = k * 64 + l;
    diag[k] = (j < PRE_K) ? C[(size_t)j * 16 + k] : 0ULL;
    sval[k] = (j < PRE_K) ? sc[j] : 0.f;
  }

  unsigned removedbits = 0;
  #pragma unroll
  for (int c = 0; c < 16; ++c) {
    unsigned long long X[16];
    #pragma unroll
    for (int w = 0; w < 16; ++w) {
      X[w] = 0ULL;
      if (w > c) {
        int j = w * 64 + l;
        if (j < PRE_K) X[w] = C[(size_t)j * 16 + c];
      }
    }
    unsigned long long sp = __ballot(sval[c] > 0.f);
    unsigned long long inc = __ballot(((removedbits >> c) & 1u) != 0u);
    unsigned long long K = sp & ~inc;
    unsigned long long col = diag[c];
    unsigned long long kept = 0;
    for (int it = 0; it < 64; ++it) {
      unsigned long long Bsupp = __ballot((col & K) != 0ULL);
      unsigned long long Snew = K & ~Bsupp & ~kept;
      if (Snew == 0ULL) break;
      kept |= Snew;
      unsigned long long Bd = __ballot((col & kept) != 0ULL);
      K &= ~Bd;
    }
    if ((col & kept) != 0ULL) removedbits |= (1u << c);
    #pragma unroll
    for (int w = 0; w < 16; ++w)
      if (w > c && (X[w] & kept) != 0ULL) removedbits |= (1u << w);
  }
  #pragma unroll
  for (int k = 0; k < 16; ++k) {
    unsigned long long w = __ballot(((removedbits >> k) & 1u) != 0u);
    if (l == 0) keepmask[(size_t)n * 16 + k] = w;
  }
}

__global__ __launch_bounds__(1024) void finalize_kernel(
    const unsigned long long* __restrict__ keepmask, const float* __restrict__ tscores,
    const float* __restrict__ tboxes, const int* __restrict__ tlabels,
    float* __restrict__ out)
{
  int n = blockIdx.x;
  int tid = threadIdx.x;
  __shared__ unsigned sk[1024];
  __shared__ unsigned sz[1024];
  bool inr = (tid < PRE_K);
  bool keep = false; float sc = 0.f;
  if (inr) {
    unsigned long long w = keepmask[(size_t)n * 16 + (tid >> 6)];
    bool rem = (w >> (tid & 63)) & 1ull;
    sc = tscores[(size_t)n * PRE_K + tid];
    keep = (!rem) && (sc > 0.f);
  }
  sk[tid] = keep ? 1u : 0u;
  sz[tid] = (inr && !keep) ? 1u : 0u;
  __syncthreads();
  for (int ofs = 1; ofs < 1024; ofs <<= 1) {
    unsigned a = (tid >= ofs) ? sk[tid - ofs] : 0;
    unsigned b = (tid >= ofs) ? sz[tid - ofs] : 0;
    __syncthreads();
    sk[tid] += a; sz[tid] += b;
    __syncthreads();
  }
  int nk = (int)sk[1023];
  int slot = -1;
  if (inr) {
    if (keep) {
      int r = (int)sk[tid] - 1;
      if (r < POST_K) slot = r;
    } else {
      int r = nk + (int)sz[tid] - 1;
      if (r < POST_K) slot = r;
    }
  }
  if (slot >= 0) {
    size_t src = (size_t)n * PRE_K + tid;
    size_t ob = ((size_t)n * POST_K + slot) * 4;
    out[ob+0] = tboxes[4*src+0];
    out[ob+1] = tboxes[4*src+1];
    out[ob+2] = tboxes[4*src+2];
    out[ob+3] = tboxes[4*src+3];
    out[(size_t)NB*POST_K*4 + (size_t)n*POST_K + slot] = keep ? sc : 0.0f;
    out[(size_t)NB*POST_K*5 + (size_t)n*POST_K + slot] = (float)tlabels[src];
  }
}

extern "C" void kernel_launch(void* const* d_in, const int* in_sizes, int n_in,
                              void* d_out, int out_size, void* d_ws, size_t ws_size,
                              hipStream_t stream) {
  char* w = (char*)d_ws;
  auto carve = [&](size_t bytes) { char* p = w; w += (bytes + 255) & ~(size_t)255; return p; };
  int* labels   = (int*)carve((size_t)NB * P_TOT * 4);
  float* boxes  = (float*)carve((size_t)NB * P_TOT * 16);
  unsigned long long* keys    = (unsigned long long*)carve((size_t)NB * P_TOT * 8);
  // ghist (4 MB) aliases colsupp (2 MB): ghist dead after scatter; colsupp
  // first written by iou (later dispatch).
  char* shared_scratch = carve((size_t)NB * 65536 * 4);
  unsigned* ghist = (unsigned*)shared_scratch;
  unsigned long long* colsupp = (unsigned long long*)shared_scratch;
  unsigned* dsel_arr = (unsigned*)carve(NB * 4);
  unsigned long long* stage = (unsigned long long*)carve((size_t)NB * 2048 * 8);
  float* tboxes  = (float*)carve((size_t)NB * PRE_K * 16);
  float* tscores = (float*)carve((size_t)NB * PRE_K * 4);
  int* tlabels   = (int*)carve((size_t)NB * PRE_K * 4);
  unsigned long long* keepmask = (unsigned long long*)carve((size_t)NB * 16 * 8);

  const float* cls0 = (const float*)d_in[0];
  const float* reg0 = (const float*)d_in[1];
  const float* ctr0 = (const float*)d_in[2];
  const float* cls1 = (const float*)d_in[3];
  const float* reg1 = (const float*)d_in[4];
  const float* ctr1 = (const float*)d_in[5];
  const float* cls2 = (const float*)d_in[6];
  const float* reg2 = (const float*)d_in[7];
  const float* ctr2 = (const float*)d_in[8];
  const float* cls3 = (const float*)d_in[9];
  const float* reg3 = (const float*)d_in[10];
  const float* ctr3 = (const float*)d_in[11];
  const float* cls4 = (const float*)d_in[12];
  const float* reg4 = (const float*)d_in[13];
  const float* ctr4 = (const float*)d_in[14];

  int n4 = NB * 65536 / 4;
  zero_kernel<<<(n4 + 255) / 256, 256, 0, stream>>>((uint4*)ghist, n4);
  dim3 dg((P4 + 63) / 64, NB);
  decode_kernel<<<dg, 256, 0, stream>>>(cls0, reg0, ctr0, cls1, reg1, ctr1,
                                        cls2, reg2, ctr2, cls3, reg3, ctr3,
                                        cls4, reg4, ctr4,
                                        labels, boxes, keys, ghist);
  selB_kernel<<<NB, 1024, 0, stream>>>(ghist, dsel_arr, stage);
  dim3 gh((P_TOT + 255) / 256, NB);
  scatter_kernel<<<gh, 256, 0, stream>>>(keys, ghist, dsel_arr, stage);
  sortG_kernel<<<NB, 1024, 0, stream>>>(stage, boxes, labels, tboxes, tscores, tlabels);
  dim3 gi(8, 16, NB);
  iou_kernel<<<gi, 128, 0, stream>>>(tboxes, tlabels, colsupp);
  greedy_kernel<<<NB, 64, 0, stream>>>(colsupp, tscores, keepmask);
  finalize_kernel<<<NB, 1024, 0, stream>>>(keepmask, tscores, tboxes, tlabels, (float*)d_out);
}

// Round 12
// 110.768 us; speedup vs baseline: 2.8022x; 1.2998x over previous
//
#include <hip/hip_runtime.h>
#include <stdint.h>

#pragma clang fp contract(off)

#define NB 16
#define NC 80
#define P_TOT 17064
#define P4 (P_TOT / 4)
#define PRE_K 1000
#define POST_K 100

__device__ __forceinline__ float sigmoidf_(float x) {
  return 1.0f / (1.0f + expf(-x));
}

// Decode (monotonicity trick: argmax over classes == argmax over raw logits;
// exact score computed once for the winner). All 20 class loads batched into
// registers BEFORE the compare chain -> ~20 loads in flight per thread.
__global__ __launch_bounds__(256, 2) void decode_kernel(
    const float* __restrict__ cls0, const float* __restrict__ reg0, const float* __restrict__ ctr0,
    const float* __restrict__ cls1, const float* __restrict__ reg1, const float* __restrict__ ctr1,
    const float* __restrict__ cls2, const float* __restrict__ reg2, const float* __restrict__ ctr2,
    const float* __restrict__ cls3, const float* __restrict__ reg3, const float* __restrict__ ctr3,
    const float* __restrict__ cls4, const float* __restrict__ reg4, const float* __restrict__ ctr4,
    int* __restrict__ labels, float* __restrict__ boxes,
    unsigned long long* __restrict__ keys)
{
  int quad = blockIdx.x * 64 + (threadIdx.x >> 2);
  int t4 = threadIdx.x & 3;
  int n = blockIdx.y;
  if (quad >= P4) return;
  int p0 = quad * 4;
  int off, wsh, hw; float stride; const float *cls, *reg, *ctr;
  if (p0 < 12800)      { off = 0;     wsh = 7; hw = 12800; stride = 8.f;   cls = cls0; reg = reg0; ctr = ctr0; }
  else if (p0 < 16000) { off = 12800; wsh = 6; hw = 3200;  stride = 16.f;  cls = cls1; reg = reg1; ctr = ctr1; }
  else if (p0 < 16800) { off = 16000; wsh = 5; hw = 800;   stride = 32.f;  cls = cls2; reg = reg2; ctr = ctr2; }
  else if (p0 < 17008) { off = 16800; wsh = 4; hw = 208;   stride = 64.f;  cls = cls3; reg = reg3; ctr = ctr3; }
  else                 { off = 17008; wsh = 3; hw = 56;    stride = 128.f; cls = cls4; reg = reg4; ctr = ctr4; }
  int loc0 = p0 - off;
  int y = loc0 >> wsh;
  int x0 = loc0 & ((1 << wsh) - 1);
  float py = (float)y * stride + 0.5f * stride;

  int c0 = t4 * 20;
  const float* cptr = cls + (size_t)n * NC * hw + (size_t)c0 * hw + loc0;
  float4 cv[20];
  #pragma unroll
  for (int k = 0; k < 20; ++k)
    cv[k] = *reinterpret_cast<const float4*>(cptr + (size_t)k * hw);

  float best[4] = { -3.4e38f, -3.4e38f, -3.4e38f, -3.4e38f };
  int bl[4] = { c0, c0, c0, c0 };
  #pragma unroll
  for (int k = 0; k < 20; ++k) {
    int c = c0 + k;
    if (cv[k].x > best[0]) { best[0] = cv[k].x; bl[0] = c; }
    if (cv[k].y > best[1]) { best[1] = cv[k].y; bl[1] = c; }
    if (cv[k].z > best[2]) { best[2] = cv[k].z; bl[2] = c; }
    if (cv[k].w > best[3]) { best[3] = cv[k].w; bl[3] = c; }
  }
  #pragma unroll
  for (int e = 0; e < 4; ++e) {
    #pragma unroll
    for (int d = 1; d <= 2; d <<= 1) {
      float ob = __shfl_xor(best[e], d);
      int ol = __shfl_xor(bl[e], d);
      if (ob > best[e] || (ob == best[e] && ol < bl[e])) { best[e] = ob; bl[e] = ol; }
    }
  }
  if (t4 != 0) return;

  float4 c4 = *reinterpret_cast<const float4*>(ctr + (size_t)n * hw + loc0);
  float sctr[4] = { sigmoidf_(c4.x), sigmoidf_(c4.y), sigmoidf_(c4.z), sigmoidf_(c4.w) };

  const float* rbase = reg + (size_t)n * 4 * hw + loc0;
  float4 rl = *reinterpret_cast<const float4*>(rbase);
  float4 rt = *reinterpret_cast<const float4*>(rbase + (size_t)hw);
  float4 rr = *reinterpret_cast<const float4*>(rbase + (size_t)2 * hw);
  float4 rb = *reinterpret_cast<const float4*>(rbase + (size_t)3 * hw);
  float dl[4] = { rl.x, rl.y, rl.z, rl.w };
  float dt[4] = { rt.x, rt.y, rt.z, rt.w };
  float dr[4] = { rr.x, rr.y, rr.z, rr.w };
  float db[4] = { rb.x, rb.y, rb.z, rb.w };

  size_t o0 = (size_t)n * P_TOT + p0;
  int4 bl4; int* blp = &bl4.x;
  unsigned long long kk[4];
  #pragma unroll
  for (int e = 0; e < 4; ++e) {
    float s = sqrtf(sigmoidf_(best[e]) * sctr[e]);
    float val = (s > 0.05f) ? s : 0.0f;
    float px = (float)(x0 + e) * stride + 0.5f * stride;
    float x1 = fminf(fmaxf(px - dl[e], 0.f), 1024.f);
    float y1 = fminf(fmaxf(py - dt[e], 0.f), 800.f);
    float x2 = fminf(fmaxf(px + dr[e], 0.f), 1024.f);
    float y2 = fminf(fmaxf(py + db[e], 0.f), 800.f);
    blp[e] = bl[e];
    *reinterpret_cast<float4*>(boxes + 4 * (o0 + e)) = make_float4(x1, y1, x2, y2);
    kk[e] = ((unsigned long long)__float_as_uint(val) << 32)
          | (unsigned long long)(0xFFFFFFFFu - (unsigned)(p0 + e));
  }
  *reinterpret_cast<int4*>(labels + o0) = bl4;
  ulonglong2 k01; k01.x = kk[0]; k01.y = kk[1];
  ulonglong2 k23; k23.x = kk[2]; k23.y = kk[3];
  *reinterpret_cast<ulonglong2*>(keys + o0) = k01;
  *reinterpret_cast<ulonglong2*>(keys + o0 + 2) = k23;
}

// LDS-binned histogram: grid (2 halves, NB). Each block counts its 32768-bin
// half in packed-u16 LDS (no global atomic contention), then direct-stores
// all bins to ghist (which therefore needs NO pre-zeroing).
__global__ __launch_bounds__(1024) void hist_kernel(
    const unsigned long long* __restrict__ keys, unsigned* __restrict__ ghist)
{
  int half = blockIdx.x;
  int n = blockIdx.y;
  int tid = threadIdx.x;
  __shared__ unsigned hcnt[16384];  // 64KB: 32768 bins as packed u16 pairs
  for (int i = tid; i < 16384; i += 1024) hcnt[i] = 0;
  __syncthreads();
  const unsigned long long* bk = keys + (size_t)n * P_TOT;
  for (int p = tid; p < P_TOT; p += 1024) {
    unsigned h = (unsigned)(bk[p] >> 48);
    if ((int)(h >> 15) == half)
      atomicAdd(&hcnt[(h & 32767u) >> 1], 1u << (16 * (h & 1u)));
  }
  __syncthreads();
  unsigned* gh = ghist + ((size_t)n << 16) + ((unsigned)half << 15);
  for (int i = tid; i < 16384; i += 1024) {
    unsigned v = hcnt[i];
    uint2 o; o.x = v & 0xFFFFu; o.y = v >> 16;
    *reinterpret_cast<uint2*>(gh + 2 * i) = o;
  }
}

// Phase B: threshold digit + per-bin base offsets + zero staging.
__global__ __launch_bounds__(1024) void selB_kernel(
    unsigned* __restrict__ ghist, unsigned* __restrict__ dsel_arr,
    unsigned long long* __restrict__ stage)
{
  int n = blockIdx.x;
  int tid = threadIdx.x;
  __shared__ unsigned A[1024];
  __shared__ unsigned s_d;

  unsigned* gh = ghist + ((size_t)n << 16);
  unsigned bvs[64];
  const uint4* gh4 = reinterpret_cast<const uint4*>(gh) + (size_t)tid * 16;
  unsigned ssum = 0;
  #pragma unroll
  for (int q = 0; q < 16; ++q) {
    uint4 v = gh4[q];
    bvs[4*q+0] = v.x; bvs[4*q+1] = v.y; bvs[4*q+2] = v.z; bvs[4*q+3] = v.w;
    ssum += v.x + v.y + v.z + v.w;
  }
  A[tid] = ssum;
  __syncthreads();
  for (int ofs = 1; ofs < 1024; ofs <<= 1) {
    unsigned v = A[tid];
    if (tid + ofs < 1024) v += A[tid + ofs];
    __syncthreads();
    A[tid] = v;
    __syncthreads();
  }
  unsigned An = (tid < 1023) ? A[tid + 1] : 0u;
  {
    unsigned At = A[tid];
    if (At >= PRE_K && An < PRE_K) {
      unsigned cum = An;
      int d = tid * 64;
      bool done = false;
      #pragma unroll
      for (int b = 63; b >= 0; --b) {
        if (!done) {
          cum += bvs[b];
          if (cum >= PRE_K) { d = tid * 64 + b; done = true; }
        }
      }
      s_d = (unsigned)d;
      dsel_arr[n] = (unsigned)d;
    }
  }
  __syncthreads();
  unsigned dsel = s_d;
  {
    unsigned cum = An;
    #pragma unroll
    for (int b = 63; b >= 0; --b) {
      unsigned h = (unsigned)(tid * 64 + b);
      if (h >= dsel && bvs[b] != 0u) gh[h] = cum;
      cum += bvs[b];
    }
  }
  stage[(size_t)n * 2048 + tid] = 0ULL;
  stage[(size_t)n * 2048 + tid + 1024] = 0ULL;
}

// Phase C: parallel bucket scatter into 2048-slot staging.
__global__ __launch_bounds__(256) void scatter_kernel(
    const unsigned long long* __restrict__ keys, unsigned* __restrict__ ghist,
    const unsigned* __restrict__ dsel_arr, unsigned long long* __restrict__ stage)
{
  int p = blockIdx.x * 256 + threadIdx.x;
  int n = blockIdx.y;
  if (p >= P_TOT) return;
  unsigned long long k = keys[(size_t)n * P_TOT + p];
  unsigned h = (unsigned)(k >> 48);
  if (h < dsel_arr[n]) return;
  unsigned old = atomicAdd(&ghist[((size_t)n << 16) + h], 0x10000u);
  unsigned slot = (old & 0xFFFFu) + (old >> 16);
  if (slot < 2048) stage[(size_t)n * 2048 + slot] = k;
}

// Phase D: bitonic sort 2048 desc + FUSED gather of boxes/labels/scores.
__global__ __launch_bounds__(1024) void sortG_kernel(
    const unsigned long long* __restrict__ stage,
    const float* __restrict__ boxes, const int* __restrict__ labels,
    float* __restrict__ tboxes, float* __restrict__ tscores, int* __restrict__ tlabels)
{
  int n = blockIdx.x;
  int tid = threadIdx.x;
  __shared__ unsigned long long skey[2048];
  skey[tid] = stage[(size_t)n * 2048 + tid];
  skey[tid + 1024] = stage[(size_t)n * 2048 + tid + 1024];
  __syncthreads();
  for (int k2 = 2; k2 <= 2048; k2 <<= 1) {
    for (int j = k2 >> 1; j > 0; j >>= 1) {
      #pragma unroll
      for (int e = 0; e < 2; ++e) {
        int idx = tid + e * 1024;
        int ixj = idx ^ j;
        if (ixj > idx) {
          unsigned long long a = skey[idx], bb = skey[ixj];
          bool sw = ((idx & k2) == 0) ? (a < bb) : (a > bb);
          if (sw) { skey[idx] = bb; skey[ixj] = a; }
        }
      }
      __syncthreads();
    }
  }
  if (tid < PRE_K) {
    unsigned long long k = skey[tid];
    unsigned idx = 0xFFFFFFFFu - (unsigned)(k & 0xFFFFFFFFu);
    float sc = __uint_as_float((unsigned)(k >> 32));
    size_t src = (size_t)n * P_TOT + idx;
    size_t dst = (size_t)n * PRE_K + tid;
    tscores[dst] = sc;
    tlabels[dst] = labels[src];
    *reinterpret_cast<float4*>(tboxes + 4 * dst) =
        *reinterpret_cast<const float4*>(boxes + 4 * src);
  }
}

// COLUMN-major suppression on a 2048-block grid (full-chip parallel).
// Divide-free guard-band; decisions bit-identical to fl(inter/denom)>0.6f.
__global__ __launch_bounds__(128) void iou_kernel(
    const float* __restrict__ tboxes, const int* __restrict__ tlabels,
    unsigned long long* __restrict__ colsupp)
{
  int jb = blockIdx.x, w = blockIdx.y, n = blockIdx.z;
  int tid = threadIdx.x;
  int j = jb * 128 + tid;
  bool jvalid = (j < PRE_K);
  int ibase = w * 64;

  if (ibase >= jb * 128 + 128) {
    if (jvalid) colsupp[((size_t)n * PRE_K + j) * 16 + w] = 0ULL;
    return;
  }

  __shared__ float4 sb[64];
  __shared__ float sa[64];
  if (tid < 64) {
    int i = ibase + tid;
    float4 v = make_float4(0.f, 0.f, 0.f, 0.f);
    if (i < PRE_K) {
      const float* b = tboxes + ((size_t)n * PRE_K + i) * 4;
      float offv = (float)tlabels[(size_t)n * PRE_K + i] * 4096.0f;
      v = make_float4(b[0] + offv, b[1] + offv, b[2] + offv, b[3] + offv);
    }
    sb[tid] = v;
    sa[tid] = (v.z - v.x) * (v.w - v.y);
  }
  __syncthreads();

  float4 bj = make_float4(0.f, 0.f, 0.f, 0.f);
  if (jvalid) {
    const float* b = tboxes + ((size_t)n * PRE_K + j) * 4;
    float offv = (float)tlabels[(size_t)n * PRE_K + j] * 4096.0f;
    bj = make_float4(b[0] + offv, b[1] + offv, b[2] + offv, b[3] + offv);
  }
  float aj = (bj.z - bj.x) * (bj.w - bj.y);

  unsigned long long m = 0, mb = 0;
  #pragma unroll
  for (int b = 0; b < 64; ++b) {
    float4 bi = sb[b];
    float ai = sa[b];
    float lx = fmaxf(bi.x, bj.x), ly = fmaxf(bi.y, bj.y);
    float rx = fminf(bi.z, bj.z), ry = fminf(bi.w, bj.w);
    float iw = fmaxf(rx - lx, 0.f), ih = fmaxf(ry - ly, 0.f);
    float inter = iw * ih;
    float denom = ai + aj - inter + 1e-9f;
    float t = inter - 0.6f * denom;
    if (t > 0.f) m |= (1ull << b);
    if (fabsf(t) <= denom * 7.62939453125e-6f) mb |= (1ull << b);  // 2^-17
  }
  if (mb) {
    unsigned long long r = mb;
    while (r) {
      int b = __ffsll(r) - 1; r &= r - 1;
      float4 bi = sb[b];
      float ai = sa[b];
      float lx = fmaxf(bi.x, bj.x), ly = fmaxf(bi.y, bj.y);
      float rx = fminf(bi.z, bj.z), ry = fminf(bi.w, bj.w);
      float iw = fmaxf(rx - lx, 0.f), ih = fmaxf(ry - ly, 0.f);
      float inter = iw * ih;
      float denom = ai + aj - inter + 1e-9f;
      float iou = inter / denom;
      if (iou > 0.6f) m |= (1ull << b); else m &= ~(1ull << b);
    }
  }
  unsigned long long tri;
  if (ibase >= j) tri = 0ULL;
  else if (j - ibase >= 64) tri = ~0ULL;
  else tri = (1ull << (j - ibase)) - 1ull;
  m &= tri;
  if (jvalid) colsupp[((size_t)n * PRE_K + j) * 16 + w] = m;
}

// One wave per batch. Fixpoint greedy (provably == sequential greedy scan).
__global__ __launch_bounds__(64, 1) void greedy_kernel(
    const unsigned long long* __restrict__ colsupp, const float* __restrict__ tscores,
    unsigned long long* __restrict__ keepmask)
{
  int n = blockIdx.x;
  int l = threadIdx.x;
  const unsigned long long* C = colsupp + (size_t)n * PRE_K * 16;
  const float* sc = tscores + (size_t)n * PRE_K;

  unsigned long long diag[16];
  float sval[16];
  #pragma unroll
  for (int k = 0; k < 16; ++k) {
    int j = k * 64 + l;
    diag[k] = (j < PRE_K) ? C[(size_t)j * 16 + k] : 0ULL;
    sval[k] = (j < PRE_K) ? sc[j] : 0.f;
  }

  unsigned removedbits = 0;
  #pragma unroll
  for (int c = 0; c < 16; ++c) {
    unsigned long long X[16];
    #pragma unroll
    for (int w = 0; w < 16; ++w) {
      X[w] = 0ULL;
      if (w > c) {
        int j = w * 64 + l;
        if (j < PRE_K) X[w] = C[(size_t)j * 16 + c];
      }
    }
    unsigned long long sp = __ballot(sval[c] > 0.f);
    unsigned long long inc = __ballot(((removedbits >> c) & 1u) != 0u);
    unsigned long long K = sp & ~inc;
    unsigned long long col = diag[c];
    unsigned long long kept = 0;
    for (int it = 0; it < 64; ++it) {
      unsigned long long Bsupp = __ballot((col & K) != 0ULL);
      unsigned long long Snew = K & ~Bsupp & ~kept;
      if (Snew == 0ULL) break;
      kept |= Snew;
      unsigned long long Bd = __ballot((col & kept) != 0ULL);
      K &= ~Bd;
    }
    if ((col & kept) != 0ULL) removedbits |= (1u << c);
    #pragma unroll
    for (int w = 0; w < 16; ++w)
      if (w > c && (X[w] & kept) != 0ULL) removedbits |= (1u << w);
  }
  #pragma unroll
  for (int k = 0; k < 16; ++k) {
    unsigned long long w = __ballot(((removedbits >> k) & 1u) != 0u);
    if (l == 0) keepmask[(size_t)n * 16 + k] = w;
  }
}

__global__ __launch_bounds__(1024) void finalize_kernel(
    const unsigned long long* __restrict__ keepmask, const float* __restrict__ tscores,
    const float* __restrict__ tboxes, const int* __restrict__ tlabels,
    float* __restrict__ out)
{
  int n = blockIdx.x;
  int tid = threadIdx.x;
  __shared__ unsigned sk[1024];
  __shared__ unsigned sz[1024];
  bool inr = (tid < PRE_K);
  bool keep = false; float sc = 0.f;
  if (inr) {
    unsigned long long w = keepmask[(size_t)n * 16 + (tid >> 6)];
    bool rem = (w >> (tid & 63)) & 1ull;
    sc = tscores[(size_t)n * PRE_K + tid];
    keep = (!rem) && (sc > 0.f);
  }
  sk[tid] = keep ? 1u : 0u;
  sz[tid] = (inr && !keep) ? 1u : 0u;
  __syncthreads();
  for (int ofs = 1; ofs < 1024; ofs <<= 1) {
    unsigned a = (tid >= ofs) ? sk[tid - ofs] : 0;
    unsigned b = (tid >= ofs) ? sz[tid - ofs] : 0;
    __syncthreads();
    sk[tid] += a; sz[tid] += b;
    __syncthreads();
  }
  int nk = (int)sk[1023];
  int slot = -1;
  if (inr) {
    if (keep) {
      int r = (int)sk[tid] - 1;
      if (r < POST_K) slot = r;
    } else {
      int r = nk + (int)sz[tid] - 1;
      if (r < POST_K) slot = r;
    }
  }
  if (slot >= 0) {
    size_t src = (size_t)n * PRE_K + tid;
    size_t ob = ((size_t)n * POST_K + slot) * 4;
    out[ob+0] = tboxes[4*src+0];
    out[ob+1] = tboxes[4*src+1];
    out[ob+2] = tboxes[4*src+2];
    out[ob+3] = tboxes[4*src+3];
    out[(size_t)NB*POST_K*4 + (size_t)n*POST_K + slot] = keep ? sc : 0.0f;
    out[(size_t)NB*POST_K*5 + (size_t)n*POST_K + slot] = (float)tlabels[src];
  }
}

extern "C" void kernel_launch(void* const* d_in, const int* in_sizes, int n_in,
                              void* d_out, int out_size, void* d_ws, size_t ws_size,
                              hipStream_t stream) {
  char* w = (char*)d_ws;
  auto carve = [&](size_t bytes) { char* p = w; w += (bytes + 255) & ~(size_t)255; return p; };
  int* labels   = (int*)carve((size_t)NB * P_TOT * 4);
  float* boxes  = (float*)carve((size_t)NB * P_TOT * 16);
  unsigned long long* keys    = (unsigned long long*)carve((size_t)NB * P_TOT * 8);
  // ghist (4 MB) aliases colsupp (2 MB): ghist dead after scatter; colsupp
  // first written by iou (later dispatch). ghist needs no pre-zero: hist_kernel
  // direct-stores every bin.
  char* shared_scratch = carve((size_t)NB * 65536 * 4);
  unsigned* ghist = (unsigned*)shared_scratch;
  unsigned long long* colsupp = (unsigned long long*)shared_scratch;
  unsigned* dsel_arr = (unsigned*)carve(NB * 4);
  unsigned long long* stage = (unsigned long long*)carve((size_t)NB * 2048 * 8);
  float* tboxes  = (float*)carve((size_t)NB * PRE_K * 16);
  float* tscores = (float*)carve((size_t)NB * PRE_K * 4);
  int* tlabels   = (int*)carve((size_t)NB * PRE_K * 4);
  unsigned long long* keepmask = (unsigned long long*)carve((size_t)NB * 16 * 8);

  const float* cls0 = (const float*)d_in[0];
  const float* reg0 = (const float*)d_in[1];
  const float* ctr0 = (const float*)d_in[2];
  const float* cls1 = (const float*)d_in[3];
  const float* reg1 = (const float*)d_in[4];
  const float* ctr1 = (const float*)d_in[5];
  const float* cls2 = (const float*)d_in[6];
  const float* reg2 = (const float*)d_in[7];
  const float* ctr2 = (const float*)d_in[8];
  const float* cls3 = (const float*)d_in[9];
  const float* reg3 = (const float*)d_in[10];
  const float* ctr3 = (const float*)d_in[11];
  const float* cls4 = (const float*)d_in[12];
  const float* reg4 = (const float*)d_in[13];
  const float* ctr4 = (const float*)d_in[14];

  dim3 dg((P4 + 63) / 64, NB);
  decode_kernel<<<dg, 256, 0, stream>>>(cls0, reg0, ctr0, cls1, reg1, ctr1,
                                        cls2, reg2, ctr2, cls3, reg3, ctr3,
                                        cls4, reg4, ctr4,
                                        labels, boxes, keys);
  dim3 gh2(2, NB);
  hist_kernel<<<gh2, 1024, 0, stream>>>(keys, ghist);
  selB_kernel<<<NB, 1024, 0, stream>>>(ghist, dsel_arr, stage);
  dim3 ghs((P_TOT + 255) / 256, NB);
  scatter_kernel<<<ghs, 256, 0, stream>>>(keys, ghist, dsel_arr, stage);
  sortG_kernel<<<NB, 1024, 0, stream>>>(stage, boxes, labels, tboxes, tscores, tlabels);
  dim3 gi(8, 16, NB);
  iou_kernel<<<gi, 128, 0, stream>>>(tboxes, tlabels, colsupp);
  greedy_kernel<<<NB, 64, 0, stream>>>(colsupp, tscores, keepmask);
  finalize_kernel<<<NB, 1024, 0, stream>>>(keepmask, tscores, tboxes, tlabels, (float*)d_out);
}

// Round 13
// 99.743 us; speedup vs baseline: 3.1119x; 1.1105x over previous
//
#include <hip/hip_runtime.h>
#include <stdint.h>

#pragma clang fp contract(off)

#define NB 16
#define NC 80
#define P_TOT 17064
#define P4 (P_TOT / 4)
#define PRE_K 1000
#define POST_K 100

__device__ __forceinline__ float sigmoidf_(float x) {
  return 1.0f / (1.0f + expf(-x));
}

// Decode (monotonicity trick: argmax over classes == argmax over raw logits;
// exact score computed once for the winner). All 20 class loads batched into
// registers BEFORE the compare chain -> ~20 loads in flight per thread.
__global__ __launch_bounds__(256, 2) void decode_kernel(
    const float* __restrict__ cls0, const float* __restrict__ reg0, const float* __restrict__ ctr0,
    const float* __restrict__ cls1, const float* __restrict__ reg1, const float* __restrict__ ctr1,
    const float* __restrict__ cls2, const float* __restrict__ reg2, const float* __restrict__ ctr2,
    const float* __restrict__ cls3, const float* __restrict__ reg3, const float* __restrict__ ctr3,
    const float* __restrict__ cls4, const float* __restrict__ reg4, const float* __restrict__ ctr4,
    int* __restrict__ labels, float* __restrict__ boxes,
    unsigned long long* __restrict__ keys)
{
  int quad = blockIdx.x * 64 + (threadIdx.x >> 2);
  int t4 = threadIdx.x & 3;
  int n = blockIdx.y;
  if (quad >= P4) return;
  int p0 = quad * 4;
  int off, wsh, hw; float stride; const float *cls, *reg, *ctr;
  if (p0 < 12800)      { off = 0;     wsh = 7; hw = 12800; stride = 8.f;   cls = cls0; reg = reg0; ctr = ctr0; }
  else if (p0 < 16000) { off = 12800; wsh = 6; hw = 3200;  stride = 16.f;  cls = cls1; reg = reg1; ctr = ctr1; }
  else if (p0 < 16800) { off = 16000; wsh = 5; hw = 800;   stride = 32.f;  cls = cls2; reg = reg2; ctr = ctr2; }
  else if (p0 < 17008) { off = 16800; wsh = 4; hw = 208;   stride = 64.f;  cls = cls3; reg = reg3; ctr = ctr3; }
  else                 { off = 17008; wsh = 3; hw = 56;    stride = 128.f; cls = cls4; reg = reg4; ctr = ctr4; }
  int loc0 = p0 - off;
  int y = loc0 >> wsh;
  int x0 = loc0 & ((1 << wsh) - 1);
  float py = (float)y * stride + 0.5f * stride;

  int c0 = t4 * 20;
  const float* cptr = cls + (size_t)n * NC * hw + (size_t)c0 * hw + loc0;
  float4 cv[20];
  #pragma unroll
  for (int k = 0; k < 20; ++k)
    cv[k] = *reinterpret_cast<const float4*>(cptr + (size_t)k * hw);

  float best[4] = { -3.4e38f, -3.4e38f, -3.4e38f, -3.4e38f };
  int bl[4] = { c0, c0, c0, c0 };
  #pragma unroll
  for (int k = 0; k < 20; ++k) {
    int c = c0 + k;
    if (cv[k].x > best[0]) { best[0] = cv[k].x; bl[0] = c; }
    if (cv[k].y > best[1]) { best[1] = cv[k].y; bl[1] = c; }
    if (cv[k].z > best[2]) { best[2] = cv[k].z; bl[2] = c; }
    if (cv[k].w > best[3]) { best[3] = cv[k].w; bl[3] = c; }
  }
  #pragma unroll
  for (int e = 0; e < 4; ++e) {
    #pragma unroll
    for (int d = 1; d <= 2; d <<= 1) {
      float ob = __shfl_xor(best[e], d);
      int ol = __shfl_xor(bl[e], d);
      if (ob > best[e] || (ob == best[e] && ol < bl[e])) { best[e] = ob; bl[e] = ol; }
    }
  }
  if (t4 != 0) return;

  float4 c4 = *reinterpret_cast<const float4*>(ctr + (size_t)n * hw + loc0);
  float sctr[4] = { sigmoidf_(c4.x), sigmoidf_(c4.y), sigmoidf_(c4.z), sigmoidf_(c4.w) };

  const float* rbase = reg + (size_t)n * 4 * hw + loc0;
  float4 rl = *reinterpret_cast<const float4*>(rbase);
  float4 rt = *reinterpret_cast<const float4*>(rbase + (size_t)hw);
  float4 rr = *reinterpret_cast<const float4*>(rbase + (size_t)2 * hw);
  float4 rb = *reinterpret_cast<const float4*>(rbase + (size_t)3 * hw);
  float dl[4] = { rl.x, rl.y, rl.z, rl.w };
  float dt[4] = { rt.x, rt.y, rt.z, rt.w };
  float dr[4] = { rr.x, rr.y, rr.z, rr.w };
  float db[4] = { rb.x, rb.y, rb.z, rb.w };

  size_t o0 = (size_t)n * P_TOT + p0;
  int4 bl4; int* blp = &bl4.x;
  unsigned long long kk[4];
  #pragma unroll
  for (int e = 0; e < 4; ++e) {
    float s = sqrtf(sigmoidf_(best[e]) * sctr[e]);
    float val = (s > 0.05f) ? s : 0.0f;
    float px = (float)(x0 + e) * stride + 0.5f * stride;
    float x1 = fminf(fmaxf(px - dl[e], 0.f), 1024.f);
    float y1 = fminf(fmaxf(py - dt[e], 0.f), 800.f);
    float x2 = fminf(fmaxf(px + dr[e], 0.f), 1024.f);
    float y2 = fminf(fmaxf(py + db[e], 0.f), 800.f);
    blp[e] = bl[e];
    *reinterpret_cast<float4*>(boxes + 4 * (o0 + e)) = make_float4(x1, y1, x2, y2);
    kk[e] = ((unsigned long long)__float_as_uint(val) << 32)
          | (unsigned long long)(0xFFFFFFFFu - (unsigned)(p0 + e));
  }
  *reinterpret_cast<int4*>(labels + o0) = bl4;
  ulonglong2 k01; k01.x = kk[0]; k01.y = kk[1];
  ulonglong2 k23; k23.x = kk[2]; k23.y = kk[3];
  *reinterpret_cast<ulonglong2*>(keys + o0) = k01;
  *reinterpret_cast<ulonglong2*>(keys + o0 + 2) = k23;
}

// Fused histogram + select. Scores lie in [0,1] so key>>48 < 0x4000 ALWAYS
// (max f32 bits 0x3F800000; val=0 -> 0). A 16384-bin u32 histogram fits in
// 64KB LDS: one block per batch, one key-stream pass, in-block suffix scan
// (16 bins/thread in registers), threshold digit dsel, base offsets written
// to ghist (only bins >= dsel; bases < 1000), staging buffer zeroed.
__global__ __launch_bounds__(1024) void histsel_kernel(
    const unsigned long long* __restrict__ keys, unsigned* __restrict__ ghist,
    unsigned* __restrict__ dsel_arr, unsigned long long* __restrict__ stage)
{
  int n = blockIdx.x;
  int tid = threadIdx.x;
  __shared__ unsigned hist[16384];
  __shared__ unsigned A[1024];
  __shared__ unsigned s_d;

  for (int i = tid; i < 16384; i += 1024) hist[i] = 0;
  __syncthreads();
  const unsigned long long* bk = keys + (size_t)n * P_TOT;
  for (int p = tid; p < P_TOT; p += 1024) {
    unsigned h = (unsigned)(bk[p] >> 48);   // < 16384 guaranteed
    atomicAdd(&hist[h], 1u);
  }
  __syncthreads();

  unsigned bvs[16];
  unsigned ssum = 0;
  #pragma unroll
  for (int q = 0; q < 16; ++q) { bvs[q] = hist[tid * 16 + q]; ssum += bvs[q]; }
  A[tid] = ssum;
  __syncthreads();
  for (int ofs = 1; ofs < 1024; ofs <<= 1) {
    unsigned v = A[tid];
    if (tid + ofs < 1024) v += A[tid + ofs];
    __syncthreads();
    A[tid] = v;
    __syncthreads();
  }
  unsigned An = (tid < 1023) ? A[tid + 1] : 0u;
  {
    unsigned At = A[tid];
    if (At >= PRE_K && An < PRE_K) {   // unique crossing strip (A monotone)
      unsigned cum = An;
      int d = tid * 16;
      bool done = false;
      #pragma unroll
      for (int b = 15; b >= 0; --b) {
        if (!done) {
          cum += bvs[b];
          if (cum >= PRE_K) { d = tid * 16 + b; done = true; }
        }
      }
      s_d = (unsigned)d;
      dsel_arr[n] = (unsigned)d;
    }
  }
  __syncthreads();
  unsigned dsel = s_d;
  {
    unsigned cum = An;
    #pragma unroll
    for (int b = 15; b >= 0; --b) {
      unsigned h = (unsigned)(tid * 16 + b);
      if (h >= dsel && bvs[b] != 0u) ghist[((size_t)n << 14) + h] = cum;
      cum += bvs[b];
    }
  }
  stage[(size_t)n * 2048 + tid] = 0ULL;
  stage[(size_t)n * 2048 + tid + 1024] = 0ULL;
}

// Parallel bucket scatter into 2048-slot staging.
__global__ __launch_bounds__(256) void scatter_kernel(
    const unsigned long long* __restrict__ keys, unsigned* __restrict__ ghist,
    const unsigned* __restrict__ dsel_arr, unsigned long long* __restrict__ stage)
{
  int p = blockIdx.x * 256 + threadIdx.x;
  int n = blockIdx.y;
  if (p >= P_TOT) return;
  unsigned long long k = keys[(size_t)n * P_TOT + p];
  unsigned h = (unsigned)(k >> 48);
  if (h < dsel_arr[n]) return;
  unsigned old = atomicAdd(&ghist[((size_t)n << 14) + h], 0x10000u);
  unsigned slot = (old & 0xFFFFu) + (old >> 16);
  if (slot < 2048) stage[(size_t)n * 2048 + slot] = k;
}

// Bitonic sort 2048 desc + fused gather of boxes/labels/scores.
__global__ __launch_bounds__(1024) void sortG_kernel(
    const unsigned long long* __restrict__ stage,
    const float* __restrict__ boxes, const int* __restrict__ labels,
    float* __restrict__ tboxes, float* __restrict__ tscores, int* __restrict__ tlabels)
{
  int n = blockIdx.x;
  int tid = threadIdx.x;
  __shared__ unsigned long long skey[2048];
  skey[tid] = stage[(size_t)n * 2048 + tid];
  skey[tid + 1024] = stage[(size_t)n * 2048 + tid + 1024];
  __syncthreads();
  for (int k2 = 2; k2 <= 2048; k2 <<= 1) {
    for (int j = k2 >> 1; j > 0; j >>= 1) {
      #pragma unroll
      for (int e = 0; e < 2; ++e) {
        int idx = tid + e * 1024;
        int ixj = idx ^ j;
        if (ixj > idx) {
          unsigned long long a = skey[idx], bb = skey[ixj];
          bool sw = ((idx & k2) == 0) ? (a < bb) : (a > bb);
          if (sw) { skey[idx] = bb; skey[ixj] = a; }
        }
      }
      __syncthreads();
    }
  }
  if (tid < PRE_K) {
    unsigned long long k = skey[tid];
    unsigned idx = 0xFFFFFFFFu - (unsigned)(k & 0xFFFFFFFFu);
    float sc = __uint_as_float((unsigned)(k >> 32));
    size_t src = (size_t)n * P_TOT + idx;
    size_t dst = (size_t)n * PRE_K + tid;
    tscores[dst] = sc;
    tlabels[dst] = labels[src];
    *reinterpret_cast<float4*>(tboxes + 4 * dst) =
        *reinterpret_cast<const float4*>(boxes + 4 * src);
  }
}

// COLUMN-major suppression on a 2048-block grid (full-chip parallel).
// Divide-free guard-band; decisions bit-identical to fl(inter/denom)>0.6f.
__global__ __launch_bounds__(128) void iou_kernel(
    const float* __restrict__ tboxes, const int* __restrict__ tlabels,
    unsigned long long* __restrict__ colsupp)
{
  int jb = blockIdx.x, w = blockIdx.y, n = blockIdx.z;
  int tid = threadIdx.x;
  int j = jb * 128 + tid;
  bool jvalid = (j < PRE_K);
  int ibase = w * 64;

  if (ibase >= jb * 128 + 128) {
    if (jvalid) colsupp[((size_t)n * PRE_K + j) * 16 + w] = 0ULL;
    return;
  }

  __shared__ float4 sb[64];
  __shared__ float sa[64];
  if (tid < 64) {
    int i = ibase + tid;
    float4 v = make_float4(0.f, 0.f, 0.f, 0.f);
    if (i < PRE_K) {
      const float* b = tboxes + ((size_t)n * PRE_K + i) * 4;
      float offv = (float)tlabels[(size_t)n * PRE_K + i] * 4096.0f;
      v = make_float4(b[0] + offv, b[1] + offv, b[2] + offv, b[3] + offv);
    }
    sb[tid] = v;
    sa[tid] = (v.z - v.x) * (v.w - v.y);
  }
  __syncthreads();

  float4 bj = make_float4(0.f, 0.f, 0.f, 0.f);
  if (jvalid) {
    const float* b = tboxes + ((size_t)n * PRE_K + j) * 4;
    float offv = (float)tlabels[(size_t)n * PRE_K + j] * 4096.0f;
    bj = make_float4(b[0] + offv, b[1] + offv, b[2] + offv, b[3] + offv);
  }
  float aj = (bj.z - bj.x) * (bj.w - bj.y);

  unsigned long long m = 0, mb = 0;
  #pragma unroll
  for (int b = 0; b < 64; ++b) {
    float4 bi = sb[b];
    float ai = sa[b];
    float lx = fmaxf(bi.x, bj.x), ly = fmaxf(bi.y, bj.y);
    float rx = fminf(bi.z, bj.z), ry = fminf(bi.w, bj.w);
    float iw = fmaxf(rx - lx, 0.f), ih = fmaxf(ry - ly, 0.f);
    float inter = iw * ih;
    float denom = ai + aj - inter + 1e-9f;
    float t = inter - 0.6f * denom;
    if (t > 0.f) m |= (1ull << b);
    if (fabsf(t) <= denom * 7.62939453125e-6f) mb |= (1ull << b);  // 2^-17
  }
  if (mb) {
    unsigned long long r = mb;
    while (r) {
      int b = __ffsll(r) - 1; r &= r - 1;
      float4 bi = sb[b];
      float ai = sa[b];
      float lx = fmaxf(bi.x, bj.x), ly = fmaxf(bi.y, bj.y);
      float rx = fminf(bi.z, bj.z), ry = fminf(bi.w, bj.w);
      float iw = fmaxf(rx - lx, 0.f), ih = fmaxf(ry - ly, 0.f);
      float inter = iw * ih;
      float denom = ai + aj - inter + 1e-9f;
      float iou = inter / denom;
      if (iou > 0.6f) m |= (1ull << b); else m &= ~(1ull << b);
    }
  }
  unsigned long long tri;
  if (ibase >= j) tri = 0ULL;
  else if (j - ibase >= 64) tri = ~0ULL;
  else tri = (1ull << (j - ibase)) - 1ull;
  m &= tri;
  if (jvalid) colsupp[((size_t)n * PRE_K + j) * 16 + w] = m;
}

// Fused greedy + finalize. Wave 0 runs the ballot-fixpoint greedy (provably
// == sequential greedy scan), storing per-chunk kept masks in LDS; then the
// whole block runs the finalize scan and writes the output.
// keep == (sc>0 && !removed_final) == bit in kept (kept ⊆ positives).
__global__ __launch_bounds__(1024) void greedyfin_kernel(
    const unsigned long long* __restrict__ colsupp, const float* __restrict__ tscores,
    const float* __restrict__ tboxes, const int* __restrict__ tlabels,
    float* __restrict__ out)
{
  int n = blockIdx.x;
  int tid = threadIdx.x;
  int wave = tid >> 6;
  int lane = tid & 63;
  __shared__ unsigned long long keptw[16];

  if (wave == 0) {
    const unsigned long long* C = colsupp + (size_t)n * PRE_K * 16;
    const float* sc = tscores + (size_t)n * PRE_K;
    unsigned long long diag[16];
    float sval[16];
    #pragma unroll
    for (int k = 0; k < 16; ++k) {
      int j = k * 64 + lane;
      diag[k] = (j < PRE_K) ? C[(size_t)j * 16 + k] : 0ULL;
      sval[k] = (j < PRE_K) ? sc[j] : 0.f;
    }
    unsigned removedbits = 0;
    #pragma unroll
    for (int c = 0; c < 16; ++c) {
      unsigned long long X[16];
      #pragma unroll
      for (int w = 0; w < 16; ++w) {
        X[w] = 0ULL;
        if (w > c) {
          int j = w * 64 + lane;
          if (j < PRE_K) X[w] = C[(size_t)j * 16 + c];
        }
      }
      unsigned long long sp = __ballot(sval[c] > 0.f);
      unsigned long long inc = __ballot(((removedbits >> c) & 1u) != 0u);
      unsigned long long K = sp & ~inc;
      unsigned long long col = diag[c];
      unsigned long long kept = 0;
      for (int it = 0; it < 64; ++it) {
        unsigned long long Bsupp = __ballot((col & K) != 0ULL);
        unsigned long long Snew = K & ~Bsupp & ~kept;
        if (Snew == 0ULL) break;
        kept |= Snew;
        unsigned long long Bd = __ballot((col & kept) != 0ULL);
        K &= ~Bd;
      }
      if ((col & kept) != 0ULL) removedbits |= (1u << c);
      #pragma unroll
      for (int w = 0; w < 16; ++w)
        if (w > c && (X[w] & kept) != 0ULL) removedbits |= (1u << w);
      if (lane == 0) keptw[c] = kept;
    }
  }
  __syncthreads();

  __shared__ unsigned sk[1024];
  __shared__ unsigned sz[1024];
  bool inr = (tid < PRE_K);
  bool keep = inr && (((keptw[tid >> 6] >> (tid & 63)) & 1ull) != 0ull);
  sk[tid] = keep ? 1u : 0u;
  sz[tid] = (inr && !keep) ? 1u : 0u;
  __syncthreads();
  for (int ofs = 1; ofs < 1024; ofs <<= 1) {
    unsigned a = (tid >= ofs) ? sk[tid - ofs] : 0;
    unsigned b = (tid >= ofs) ? sz[tid - ofs] : 0;
    __syncthreads();
    sk[tid] += a; sz[tid] += b;
    __syncthreads();
  }
  int nk = (int)sk[1023];
  int slot = -1;
  if (inr) {
    if (keep) {
      int r = (int)sk[tid] - 1;
      if (r < POST_K) slot = r;
    } else {
      int r = nk + (int)sz[tid] - 1;
      if (r < POST_K) slot = r;
    }
  }
  if (slot >= 0) {
    size_t src = (size_t)n * PRE_K + tid;
    size_t ob = ((size_t)n * POST_K + slot) * 4;
    out[ob+0] = tboxes[4*src+0];
    out[ob+1] = tboxes[4*src+1];
    out[ob+2] = tboxes[4*src+2];
    out[ob+3] = tboxes[4*src+3];
    out[(size_t)NB*POST_K*4 + (size_t)n*POST_K + slot] = keep ? tscores[src] : 0.0f;
    out[(size_t)NB*POST_K*5 + (size_t)n*POST_K + slot] = (float)tlabels[src];
  }
}

extern "C" void kernel_launch(void* const* d_in, const int* in_sizes, int n_in,
                              void* d_out, int out_size, void* d_ws, size_t ws_size,
                              hipStream_t stream) {
  char* w = (char*)d_ws;
  auto carve = [&](size_t bytes) { char* p = w; w += (bytes + 255) & ~(size_t)255; return p; };
  int* labels   = (int*)carve((size_t)NB * P_TOT * 4);
  float* boxes  = (float*)carve((size_t)NB * P_TOT * 16);
  unsigned long long* keys    = (unsigned long long*)carve((size_t)NB * P_TOT * 8);
  // ghist (1 MB, 16384 bins/batch) aliases colsupp (2 MB): ghist dead after
  // scatter; colsupp first written by iou (later dispatch). Carve the max.
  char* shared_scratch = carve((size_t)NB * PRE_K * 16 * 8);
  unsigned* ghist = (unsigned*)shared_scratch;
  unsigned long long* colsupp = (unsigned long long*)shared_scratch;
  unsigned* dsel_arr = (unsigned*)carve(NB * 4);
  unsigned long long* stage = (unsigned long long*)carve((size_t)NB * 2048 * 8);
  float* tboxes  = (float*)carve((size_t)NB * PRE_K * 16);
  float* tscores = (float*)carve((size_t)NB * PRE_K * 4);
  int* tlabels   = (int*)carve((size_t)NB * PRE_K * 4);

  const float* cls0 = (const float*)d_in[0];
  const float* reg0 = (const float*)d_in[1];
  const float* ctr0 = (const float*)d_in[2];
  const float* cls1 = (const float*)d_in[3];
  const float* reg1 = (const float*)d_in[4];
  const float* ctr1 = (const float*)d_in[5];
  const float* cls2 = (const float*)d_in[6];
  const float* reg2 = (const float*)d_in[7];
  const float* ctr2 = (const float*)d_in[8];
  const float* cls3 = (const float*)d_in[9];
  const float* reg3 = (const float*)d_in[10];
  const float* ctr3 = (const float*)d_in[11];
  const float* cls4 = (const float*)d_in[12];
  const float* reg4 = (const float*)d_in[13];
  const float* ctr4 = (const float*)d_in[14];

  dim3 dg((P4 + 63) / 64, NB);
  decode_kernel<<<dg, 256, 0, stream>>>(cls0, reg0, ctr0, cls1, reg1, ctr1,
                                        cls2, reg2, ctr2, cls3, reg3, ctr3,
                                        cls4, reg4, ctr4,
                                        labels, boxes, keys);
  histsel_kernel<<<NB, 1024, 0, stream>>>(keys, ghist, dsel_arr, stage);
  dim3 ghs((P_TOT + 255) / 256, NB);
  scatter_kernel<<<ghs, 256, 0, stream>>>(keys, ghist, dsel_arr, stage);
  sortG_kernel<<<NB, 1024, 0, stream>>>(stage, boxes, labels, tboxes, tscores, tlabels);
  dim3 gi(8, 16, NB);
  iou_kernel<<<gi, 128, 0, stream>>>(tboxes, tlabels, colsupp);
  greedyfin_kernel<<<NB, 1024, 0, stream>>>(colsupp, tscores, tboxes, tlabels, (float*)d_out);
}

// Round 14
// 94.633 us; speedup vs baseline: 3.2800x; 1.0540x over previous
//
#include <hip/hip_runtime.h>
#include <stdint.h>

#pragma clang fp contract(off)

#define NB 16
#define NC 80
#define P_TOT 17064
#define P4 (P_TOT / 4)
#define PRE_K 1000
#define POST_K 100

__device__ __forceinline__ float sigmoidf_(float x) {
  return 1.0f / (1.0f + expf(-x));
}

// Decode (monotonicity trick: argmax over classes == argmax over raw logits;
// exact score computed once for the winner). All 20 class loads batched into
// registers BEFORE the compare chain -> ~20 loads in flight per thread.
__global__ __launch_bounds__(256, 2) void decode_kernel(
    const float* __restrict__ cls0, const float* __restrict__ reg0, const float* __restrict__ ctr0,
    const float* __restrict__ cls1, const float* __restrict__ reg1, const float* __restrict__ ctr1,
    const float* __restrict__ cls2, const float* __restrict__ reg2, const float* __restrict__ ctr2,
    const float* __restrict__ cls3, const float* __restrict__ reg3, const float* __restrict__ ctr3,
    const float* __restrict__ cls4, const float* __restrict__ reg4, const float* __restrict__ ctr4,
    int* __restrict__ labels, float* __restrict__ boxes,
    unsigned long long* __restrict__ keys)
{
  int quad = blockIdx.x * 64 + (threadIdx.x >> 2);
  int t4 = threadIdx.x & 3;
  int n = blockIdx.y;
  if (quad >= P4) return;
  int p0 = quad * 4;
  int off, wsh, hw; float stride; const float *cls, *reg, *ctr;
  if (p0 < 12800)      { off = 0;     wsh = 7; hw = 12800; stride = 8.f;   cls = cls0; reg = reg0; ctr = ctr0; }
  else if (p0 < 16000) { off = 12800; wsh = 6; hw = 3200;  stride = 16.f;  cls = cls1; reg = reg1; ctr = ctr1; }
  else if (p0 < 16800) { off = 16000; wsh = 5; hw = 800;   stride = 32.f;  cls = cls2; reg = reg2; ctr = ctr2; }
  else if (p0 < 17008) { off = 16800; wsh = 4; hw = 208;   stride = 64.f;  cls = cls3; reg = reg3; ctr = ctr3; }
  else                 { off = 17008; wsh = 3; hw = 56;    stride = 128.f; cls = cls4; reg = reg4; ctr = ctr4; }
  int loc0 = p0 - off;
  int y = loc0 >> wsh;
  int x0 = loc0 & ((1 << wsh) - 1);
  float py = (float)y * stride + 0.5f * stride;

  int c0 = t4 * 20;
  const float* cptr = cls + (size_t)n * NC * hw + (size_t)c0 * hw + loc0;
  float4 cv[20];
  #pragma unroll
  for (int k = 0; k < 20; ++k)
    cv[k] = *reinterpret_cast<const float4*>(cptr + (size_t)k * hw);

  float best[4] = { -3.4e38f, -3.4e38f, -3.4e38f, -3.4e38f };
  int bl[4] = { c0, c0, c0, c0 };
  #pragma unroll
  for (int k = 0; k < 20; ++k) {
    int c = c0 + k;
    if (cv[k].x > best[0]) { best[0] = cv[k].x; bl[0] = c; }
    if (cv[k].y > best[1]) { best[1] = cv[k].y; bl[1] = c; }
    if (cv[k].z > best[2]) { best[2] = cv[k].z; bl[2] = c; }
    if (cv[k].w > best[3]) { best[3] = cv[k].w; bl[3] = c; }
  }
  #pragma unroll
  for (int e = 0; e < 4; ++e) {
    #pragma unroll
    for (int d = 1; d <= 2; d <<= 1) {
      float ob = __shfl_xor(best[e], d);
      int ol = __shfl_xor(bl[e], d);
      if (ob > best[e] || (ob == best[e] && ol < bl[e])) { best[e] = ob; bl[e] = ol; }
    }
  }
  if (t4 != 0) return;

  float4 c4 = *reinterpret_cast<const float4*>(ctr + (size_t)n * hw + loc0);
  float sctr[4] = { sigmoidf_(c4.x), sigmoidf_(c4.y), sigmoidf_(c4.z), sigmoidf_(c4.w) };

  const float* rbase = reg + (size_t)n * 4 * hw + loc0;
  float4 rl = *reinterpret_cast<const float4*>(rbase);
  float4 rt = *reinterpret_cast<const float4*>(rbase + (size_t)hw);
  float4 rr = *reinterpret_cast<const float4*>(rbase + (size_t)2 * hw);
  float4 rb = *reinterpret_cast<const float4*>(rbase + (size_t)3 * hw);
  float dl[4] = { rl.x, rl.y, rl.z, rl.w };
  float dt[4] = { rt.x, rt.y, rt.z, rt.w };
  float dr[4] = { rr.x, rr.y, rr.z, rr.w };
  float db[4] = { rb.x, rb.y, rb.z, rb.w };

  size_t o0 = (size_t)n * P_TOT + p0;
  int4 bl4; int* blp = &bl4.x;
  unsigned long long kk[4];
  #pragma unroll
  for (int e = 0; e < 4; ++e) {
    float s = sqrtf(sigmoidf_(best[e]) * sctr[e]);
    float val = (s > 0.05f) ? s : 0.0f;
    float px = (float)(x0 + e) * stride + 0.5f * stride;
    float x1 = fminf(fmaxf(px - dl[e], 0.f), 1024.f);
    float y1 = fminf(fmaxf(py - dt[e], 0.f), 800.f);
    float x2 = fminf(fmaxf(px + dr[e], 0.f), 1024.f);
    float y2 = fminf(fmaxf(py + db[e], 0.f), 800.f);
    blp[e] = bl[e];
    *reinterpret_cast<float4*>(boxes + 4 * (o0 + e)) = make_float4(x1, y1, x2, y2);
    kk[e] = ((unsigned long long)__float_as_uint(val) << 32)
          | (unsigned long long)(0xFFFFFFFFu - (unsigned)(p0 + e));
  }
  *reinterpret_cast<int4*>(labels + o0) = bl4;
  ulonglong2 k01; k01.x = kk[0]; k01.y = kk[1];
  ulonglong2 k23; k23.x = kk[2]; k23.y = kk[3];
  *reinterpret_cast<ulonglong2*>(keys + o0) = k01;
  *reinterpret_cast<ulonglong2*>(keys + o0 + 2) = k23;
}

// Fully-fused top-k: one block per batch, all state in LDS.
// Scores lie in [0,1] so key>>48 < 0x4000 always -> 16384-bin u32 LDS hist.
// Pass 1: histogram. Suffix-scan -> threshold digit dsel (smallest top-16
// with suffix count >= 1000). Bins >= dsel overwritten with BASE offsets
// (count of keys in bins > h) in LDS. Pass 2: scatter candidates into LDS
// skey[2048] via LDS atomicAdd on base (slots unique, bin-ordered; same
// semantics + <2048 guard as the previous global scheme). Bitonic sort 2048
// desc, then fused gather of boxes/labels/scores for the top 1000.
__global__ __launch_bounds__(1024) void topgather_kernel(
    const unsigned long long* __restrict__ keys,
    const float* __restrict__ boxes, const int* __restrict__ labels,
    float* __restrict__ tboxes, float* __restrict__ tscores, int* __restrict__ tlabels)
{
  int n = blockIdx.x;
  int tid = threadIdx.x;
  __shared__ unsigned hist[16384];
  __shared__ unsigned A[1024];
  __shared__ unsigned s_d;
  __shared__ unsigned long long skey[2048];

  for (int i = tid; i < 16384; i += 1024) hist[i] = 0;
  skey[tid] = 0ULL;
  skey[tid + 1024] = 0ULL;
  __syncthreads();
  const unsigned long long* bk = keys + (size_t)n * P_TOT;
  for (int p = tid; p < P_TOT; p += 1024) {
    unsigned h = (unsigned)(bk[p] >> 48);   // < 16384 guaranteed
    atomicAdd(&hist[h], 1u);
  }
  __syncthreads();

  unsigned bvs[16];
  unsigned ssum = 0;
  #pragma unroll
  for (int q = 0; q < 16; ++q) { bvs[q] = hist[tid * 16 + q]; ssum += bvs[q]; }
  A[tid] = ssum;
  __syncthreads();
  for (int ofs = 1; ofs < 1024; ofs <<= 1) {
    unsigned v = A[tid];
    if (tid + ofs < 1024) v += A[tid + ofs];
    __syncthreads();
    A[tid] = v;
    __syncthreads();
  }
  unsigned An = (tid < 1023) ? A[tid + 1] : 0u;
  {
    unsigned At = A[tid];
    if (At >= PRE_K && An < PRE_K) {   // unique crossing strip (A monotone)
      unsigned cum = An;
      int d = tid * 16;
      bool done = false;
      #pragma unroll
      for (int b = 15; b >= 0; --b) {
        if (!done) {
          cum += bvs[b];
          if (cum >= PRE_K) { d = tid * 16 + b; done = true; }
        }
      }
      s_d = (unsigned)d;
    }
  }
  __syncthreads();
  unsigned dsel = s_d;
  // overwrite bins >= dsel with base offsets (keys in bins > h)
  {
    unsigned cum = An;
    #pragma unroll
    for (int b = 15; b >= 0; --b) {
      unsigned h = (unsigned)(tid * 16 + b);
      if (h >= dsel) hist[h] = cum;
      cum += bvs[b];
    }
  }
  __syncthreads();
  // pass 2: scatter candidates into LDS staging
  for (int p = tid; p < P_TOT; p += 1024) {
    unsigned long long k = bk[p];
    unsigned h = (unsigned)(k >> 48);
    if (h >= dsel) {
      unsigned slot = atomicAdd(&hist[h], 1u);
      if (slot < 2048) skey[slot] = k;
    }
  }
  __syncthreads();
  // bitonic sort 2048 desc
  for (int k2 = 2; k2 <= 2048; k2 <<= 1) {
    for (int j = k2 >> 1; j > 0; j >>= 1) {
      #pragma unroll
      for (int e = 0; e < 2; ++e) {
        int idx = tid + e * 1024;
        int ixj = idx ^ j;
        if (ixj > idx) {
          unsigned long long a = skey[idx], bb = skey[ixj];
          bool sw = ((idx & k2) == 0) ? (a < bb) : (a > bb);
          if (sw) { skey[idx] = bb; skey[ixj] = a; }
        }
      }
      __syncthreads();
    }
  }
  if (tid < PRE_K) {
    unsigned long long k = skey[tid];
    unsigned idx = 0xFFFFFFFFu - (unsigned)(k & 0xFFFFFFFFu);
    float sc = __uint_as_float((unsigned)(k >> 32));
    size_t src = (size_t)n * P_TOT + idx;
    size_t dst = (size_t)n * PRE_K + tid;
    tscores[dst] = sc;
    tlabels[dst] = labels[src];
    *reinterpret_cast<float4*>(tboxes + 4 * dst) =
        *reinterpret_cast<const float4*>(boxes + 4 * src);
  }
}

// COLUMN-major suppression on a 2048-block grid (full-chip parallel).
// Divide-free guard-band; decisions bit-identical to fl(inter/denom)>0.6f.
__global__ __launch_bounds__(128) void iou_kernel(
    const float* __restrict__ tboxes, const int* __restrict__ tlabels,
    unsigned long long* __restrict__ colsupp)
{
  int jb = blockIdx.x, w = blockIdx.y, n = blockIdx.z;
  int tid = threadIdx.x;
  int j = jb * 128 + tid;
  bool jvalid = (j < PRE_K);
  int ibase = w * 64;

  if (ibase >= jb * 128 + 128) {
    if (jvalid) colsupp[((size_t)n * PRE_K + j) * 16 + w] = 0ULL;
    return;
  }

  __shared__ float4 sb[64];
  __shared__ float sa[64];
  if (tid < 64) {
    int i = ibase + tid;
    float4 v = make_float4(0.f, 0.f, 0.f, 0.f);
    if (i < PRE_K) {
      const float* b = tboxes + ((size_t)n * PRE_K + i) * 4;
      float offv = (float)tlabels[(size_t)n * PRE_K + i] * 4096.0f;
      v = make_float4(b[0] + offv, b[1] + offv, b[2] + offv, b[3] + offv);
    }
    sb[tid] = v;
    sa[tid] = (v.z - v.x) * (v.w - v.y);
  }
  __syncthreads();

  float4 bj = make_float4(0.f, 0.f, 0.f, 0.f);
  if (jvalid) {
    const float* b = tboxes + ((size_t)n * PRE_K + j) * 4;
    float offv = (float)tlabels[(size_t)n * PRE_K + j] * 4096.0f;
    bj = make_float4(b[0] + offv, b[1] + offv, b[2] + offv, b[3] + offv);
  }
  float aj = (bj.z - bj.x) * (bj.w - bj.y);

  unsigned long long m = 0, mb = 0;
  #pragma unroll
  for (int b = 0; b < 64; ++b) {
    float4 bi = sb[b];
    float ai = sa[b];
    float lx = fmaxf(bi.x, bj.x), ly = fmaxf(bi.y, bj.y);
    float rx = fminf(bi.z, bj.z), ry = fminf(bi.w, bj.w);
    float iw = fmaxf(rx - lx, 0.f), ih = fmaxf(ry - ly, 0.f);
    float inter = iw * ih;
    float denom = ai + aj - inter + 1e-9f;
    float t = inter - 0.6f * denom;
    if (t > 0.f) m |= (1ull << b);
    if (fabsf(t) <= denom * 7.62939453125e-6f) mb |= (1ull << b);  // 2^-17
  }
  if (mb) {
    unsigned long long r = mb;
    while (r) {
      int b = __ffsll(r) - 1; r &= r - 1;
      float4 bi = sb[b];
      float ai = sa[b];
      float lx = fmaxf(bi.x, bj.x), ly = fmaxf(bi.y, bj.y);
      float rx = fminf(bi.z, bj.z), ry = fminf(bi.w, bj.w);
      float iw = fmaxf(rx - lx, 0.f), ih = fmaxf(ry - ly, 0.f);
      float inter = iw * ih;
      float denom = ai + aj - inter + 1e-9f;
      float iou = inter / denom;
      if (iou > 0.6f) m |= (1ull << b); else m &= ~(1ull << b);
    }
  }
  unsigned long long tri;
  if (ibase >= j) tri = 0ULL;
  else if (j - ibase >= 64) tri = ~0ULL;
  else tri = (1ull << (j - ibase)) - 1ull;
  m &= tri;
  if (jvalid) colsupp[((size_t)n * PRE_K + j) * 16 + w] = m;
}

// Fused greedy + finalize. Wave 0 runs the ballot-fixpoint greedy (provably
// == sequential greedy scan), storing per-chunk kept masks in LDS; then the
// whole block runs the finalize scan and writes the output.
__global__ __launch_bounds__(1024) void greedyfin_kernel(
    const unsigned long long* __restrict__ colsupp, const float* __restrict__ tscores,
    const float* __restrict__ tboxes, const int* __restrict__ tlabels,
    float* __restrict__ out)
{
  int n = blockIdx.x;
  int tid = threadIdx.x;
  int wave = tid >> 6;
  int lane = tid & 63;
  __shared__ unsigned long long keptw[16];

  if (wave == 0) {
    const unsigned long long* C = colsupp + (size_t)n * PRE_K * 16;
    const float* sc = tscores + (size_t)n * PRE_K;
    unsigned long long diag[16];
    float sval[16];
    #pragma unroll
    for (int k = 0; k < 16; ++k) {
      int j = k * 64 + lane;
      diag[k] = (j < PRE_K) ? C[(size_t)j * 16 + k] : 0ULL;
      sval[k] = (j < PRE_K) ? sc[j] : 0.f;
    }
    unsigned removedbits = 0;
    #pragma unroll
    for (int c = 0; c < 16; ++c) {
      unsigned long long X[16];
      #pragma unroll
      for (int w = 0; w < 16; ++w) {
        X[w] = 0ULL;
        if (w > c) {
          int j = w * 64 + lane;
          if (j < PRE_K) X[w] = C[(size_t)j * 16 + c];
        }
      }
      unsigned long long sp = __ballot(sval[c] > 0.f);
      unsigned long long inc = __ballot(((removedbits >> c) & 1u) != 0u);
      unsigned long long K = sp & ~inc;
      unsigned long long col = diag[c];
      unsigned long long kept = 0;
      for (int it = 0; it < 64; ++it) {
        unsigned long long Bsupp = __ballot((col & K) != 0ULL);
        unsigned long long Snew = K & ~Bsupp & ~kept;
        if (Snew == 0ULL) break;
        kept |= Snew;
        unsigned long long Bd = __ballot((col & kept) != 0ULL);
        K &= ~Bd;
      }
      if ((col & kept) != 0ULL) removedbits |= (1u << c);
      #pragma unroll
      for (int w = 0; w < 16; ++w)
        if (w > c && (X[w] & kept) != 0ULL) removedbits |= (1u << w);
      if (lane == 0) keptw[c] = kept;
    }
  }
  __syncthreads();

  __shared__ unsigned sk[1024];
  __shared__ unsigned sz[1024];
  bool inr = (tid < PRE_K);
  bool keep = inr && (((keptw[tid >> 6] >> (tid & 63)) & 1ull) != 0ull);
  sk[tid] = keep ? 1u : 0u;
  sz[tid] = (inr && !keep) ? 1u : 0u;
  __syncthreads();
  for (int ofs = 1; ofs < 1024; ofs <<= 1) {
    unsigned a = (tid >= ofs) ? sk[tid - ofs] : 0;
    unsigned b = (tid >= ofs) ? sz[tid - ofs] : 0;
    __syncthreads();
    sk[tid] += a; sz[tid] += b;
    __syncthreads();
  }
  int nk = (int)sk[1023];
  int slot = -1;
  if (inr) {
    if (keep) {
      int r = (int)sk[tid] - 1;
      if (r < POST_K) slot = r;
    } else {
      int r = nk + (int)sz[tid] - 1;
      if (r < POST_K) slot = r;
    }
  }
  if (slot >= 0) {
    size_t src = (size_t)n * PRE_K + tid;
    size_t ob = ((size_t)n * POST_K + slot) * 4;
    out[ob+0] = tboxes[4*src+0];
    out[ob+1] = tboxes[4*src+1];
    out[ob+2] = tboxes[4*src+2];
    out[ob+3] = tboxes[4*src+3];
    out[(size_t)NB*POST_K*4 + (size_t)n*POST_K + slot] = keep ? tscores[src] : 0.0f;
    out[(size_t)NB*POST_K*5 + (size_t)n*POST_K + slot] = (float)tlabels[src];
  }
}

extern "C" void kernel_launch(void* const* d_in, const int* in_sizes, int n_in,
                              void* d_out, int out_size, void* d_ws, size_t ws_size,
                              hipStream_t stream) {
  char* w = (char*)d_ws;
  auto carve = [&](size_t bytes) { char* p = w; w += (bytes + 255) & ~(size_t)255; return p; };
  int* labels   = (int*)carve((size_t)NB * P_TOT * 4);
  float* boxes  = (float*)carve((size_t)NB * P_TOT * 16);
  unsigned long long* keys = (unsigned long long*)carve((size_t)NB * P_TOT * 8);
  unsigned long long* colsupp = (unsigned long long*)carve((size_t)NB * PRE_K * 16 * 8);
  float* tboxes  = (float*)carve((size_t)NB * PRE_K * 16);
  float* tscores = (float*)carve((size_t)NB * PRE_K * 4);
  int* tlabels   = (int*)carve((size_t)NB * PRE_K * 4);

  const float* cls0 = (const float*)d_in[0];
  const float* reg0 = (const float*)d_in[1];
  const float* ctr0 = (const float*)d_in[2];
  const float* cls1 = (const float*)d_in[3];
  const float* reg1 = (const float*)d_in[4];
  const float* ctr1 = (const float*)d_in[5];
  const float* cls2 = (const float*)d_in[6];
  const float* reg2 = (const float*)d_in[7];
  const float* ctr2 = (const float*)d_in[8];
  const float* cls3 = (const float*)d_in[9];
  const float* reg3 = (const float*)d_in[10];
  const float* ctr3 = (const float*)d_in[11];
  const float* cls4 = (const float*)d_in[12];
  const float* reg4 = (const float*)d_in[13];
  const float* ctr4 = (const float*)d_in[14];

  dim3 dg((P4 + 63) / 64, NB);
  decode_kernel<<<dg, 256, 0, stream>>>(cls0, reg0, ctr0, cls1, reg1, ctr1,
                                        cls2, reg2, ctr2, cls3, reg3, ctr3,
                                        cls4, reg4, ctr4,
                                        labels, boxes, keys);
  topgather_kernel<<<NB, 1024, 0, stream>>>(keys, boxes, labels,
                                            tboxes, tscores, tlabels);
  dim3 gi(8, 16, NB);
  iou_kernel<<<gi, 128, 0, stream>>>(tboxes, tlabels, colsupp);
  greedyfin_kernel<<<NB, 1024, 0, stream>>>(colsupp, tscores, tboxes, tlabels, (float*)d_out);
}

// Round 15
// 83.049 us; speedup vs baseline: 3.7374x; 1.1395x over previous
//
#include <hip/hip_runtime.h>
#include <stdint.h>

#pragma clang fp contract(off)

#define NB 16
#define NC 80
#define P_TOT 17064
#define P4 (P_TOT / 4)
#define PRE_K 1000
#define POST_K 100

__device__ __forceinline__ float sigmoidf_(float x) {
  return 1.0f / (1.0f + expf(-x));
}

// Decode (monotonicity trick: argmax over classes == argmax over raw logits;
// exact score computed once for the winner). 20 class loads batched into
// registers; after the quad-reduce each lane decodes its OWN location
// (all lanes active in the epilogue; same arithmetic, same bytes stored).
__global__ __launch_bounds__(256, 2) void decode_kernel(
    const float* __restrict__ cls0, const float* __restrict__ reg0, const float* __restrict__ ctr0,
    const float* __restrict__ cls1, const float* __restrict__ reg1, const float* __restrict__ ctr1,
    const float* __restrict__ cls2, const float* __restrict__ reg2, const float* __restrict__ ctr2,
    const float* __restrict__ cls3, const float* __restrict__ reg3, const float* __restrict__ ctr3,
    const float* __restrict__ cls4, const float* __restrict__ reg4, const float* __restrict__ ctr4,
    int* __restrict__ labels, float* __restrict__ boxes,
    unsigned long long* __restrict__ keys)
{
  int quad = blockIdx.x * 64 + (threadIdx.x >> 2);
  int t4 = threadIdx.x & 3;
  int n = blockIdx.y;
  if (quad >= P4) return;
  int p0 = quad * 4;
  int off, wsh, hw; float stride; const float *cls, *reg, *ctr;
  if (p0 < 12800)      { off = 0;     wsh = 7; hw = 12800; stride = 8.f;   cls = cls0; reg = reg0; ctr = ctr0; }
  else if (p0 < 16000) { off = 12800; wsh = 6; hw = 3200;  stride = 16.f;  cls = cls1; reg = reg1; ctr = ctr1; }
  else if (p0 < 16800) { off = 16000; wsh = 5; hw = 800;   stride = 32.f;  cls = cls2; reg = reg2; ctr = ctr2; }
  else if (p0 < 17008) { off = 16800; wsh = 4; hw = 208;   stride = 64.f;  cls = cls3; reg = reg3; ctr = ctr3; }
  else                 { off = 17008; wsh = 3; hw = 56;    stride = 128.f; cls = cls4; reg = reg4; ctr = ctr4; }
  int loc0 = p0 - off;
  int y = loc0 >> wsh;
  int x0 = loc0 & ((1 << wsh) - 1);
  float py = (float)y * stride + 0.5f * stride;

  int c0 = t4 * 20;
  const float* cptr = cls + (size_t)n * NC * hw + (size_t)c0 * hw + loc0;
  float4 cv[20];
  #pragma unroll
  for (int k = 0; k < 20; ++k)
    cv[k] = *reinterpret_cast<const float4*>(cptr + (size_t)k * hw);

  float best[4] = { -3.4e38f, -3.4e38f, -3.4e38f, -3.4e38f };
  int bl[4] = { c0, c0, c0, c0 };
  #pragma unroll
  for (int k = 0; k < 20; ++k) {
    int c = c0 + k;
    if (cv[k].x > best[0]) { best[0] = cv[k].x; bl[0] = c; }
    if (cv[k].y > best[1]) { best[1] = cv[k].y; bl[1] = c; }
    if (cv[k].z > best[2]) { best[2] = cv[k].z; bl[2] = c; }
    if (cv[k].w > best[3]) { best[3] = cv[k].w; bl[3] = c; }
  }
  #pragma unroll
  for (int e = 0; e < 4; ++e) {
    #pragma unroll
    for (int d = 1; d <= 2; d <<= 1) {
      float ob = __shfl_xor(best[e], d);
      int ol = __shfl_xor(bl[e], d);
      if (ob > best[e] || (ob == best[e] && ol < bl[e])) { best[e] = ob; bl[e] = ol; }
    }
  }

  // per-lane epilogue: lane e owns location p0+e (all values bit-identical
  // to the former lane0-serial path).
  int e = t4;
  int loce = loc0 + e;
  float sctr_e = sigmoidf_(ctr[(size_t)n * hw + loce]);
  const float* rbase = reg + (size_t)n * 4 * hw + loce;
  float dl = rbase[0];
  float dt = rbase[(size_t)hw];
  float dr = rbase[(size_t)2 * hw];
  float db = rbase[(size_t)3 * hw];

  float s = sqrtf(sigmoidf_(best[e]) * sctr_e);
  float val = (s > 0.05f) ? s : 0.0f;
  float px = (float)(x0 + e) * stride + 0.5f * stride;
  float x1 = fminf(fmaxf(px - dl, 0.f), 1024.f);
  float y1 = fminf(fmaxf(py - dt, 0.f), 800.f);
  float x2 = fminf(fmaxf(px + dr, 0.f), 1024.f);
  float y2 = fminf(fmaxf(py + db, 0.f), 800.f);

  size_t o = (size_t)n * P_TOT + p0 + e;
  labels[o] = bl[e];
  *reinterpret_cast<float4*>(boxes + 4 * o) = make_float4(x1, y1, x2, y2);
  keys[o] = ((unsigned long long)__float_as_uint(val) << 32)
          | (unsigned long long)(0xFFFFFFFFu - (unsigned)(p0 + e));
}

// Fully-fused top-k: one block per batch, all state in LDS.
// Scores lie in [0,1] so key>>48 < 0x4000 always -> 16384-bin u32 LDS hist.
__global__ __launch_bounds__(1024) void topgather_kernel(
    const unsigned long long* __restrict__ keys,
    const float* __restrict__ boxes, const int* __restrict__ labels,
    float* __restrict__ tboxes, float* __restrict__ tscores, int* __restrict__ tlabels)
{
  int n = blockIdx.x;
  int tid = threadIdx.x;
  __shared__ unsigned hist[16384];
  __shared__ unsigned A[1024];
  __shared__ unsigned s_d;
  __shared__ unsigned long long skey[2048];

  for (int i = tid; i < 16384; i += 1024) hist[i] = 0;
  skey[tid] = 0ULL;
  skey[tid + 1024] = 0ULL;
  __syncthreads();
  const unsigned long long* bk = keys + (size_t)n * P_TOT;
  for (int p = tid; p < P_TOT; p += 1024) {
    unsigned h = (unsigned)(bk[p] >> 48);   // < 16384 guaranteed
    atomicAdd(&hist[h], 1u);
  }
  __syncthreads();

  unsigned bvs[16];
  unsigned ssum = 0;
  #pragma unroll
  for (int q = 0; q < 16; ++q) { bvs[q] = hist[tid * 16 + q]; ssum += bvs[q]; }
  A[tid] = ssum;
  __syncthreads();
  for (int ofs = 1; ofs < 1024; ofs <<= 1) {
    unsigned v = A[tid];
    if (tid + ofs < 1024) v += A[tid + ofs];
    __syncthreads();
    A[tid] = v;
    __syncthreads();
  }
  unsigned An = (tid < 1023) ? A[tid + 1] : 0u;
  {
    unsigned At = A[tid];
    if (At >= PRE_K && An < PRE_K) {   // unique crossing strip (A monotone)
      unsigned cum = An;
      int d = tid * 16;
      bool done = false;
      #pragma unroll
      for (int b = 15; b >= 0; --b) {
        if (!done) {
          cum += bvs[b];
          if (cum >= PRE_K) { d = tid * 16 + b; done = true; }
        }
      }
      s_d = (unsigned)d;
    }
  }
  __syncthreads();
  unsigned dsel = s_d;
  {
    unsigned cum = An;
    #pragma unroll
    for (int b = 15; b >= 0; --b) {
      unsigned h = (unsigned)(tid * 16 + b);
      if (h >= dsel) hist[h] = cum;
      cum += bvs[b];
    }
  }
  __syncthreads();
  for (int p = tid; p < P_TOT; p += 1024) {
    unsigned long long k = bk[p];
    unsigned h = (unsigned)(k >> 48);
    if (h >= dsel) {
      unsigned slot = atomicAdd(&hist[h], 1u);
      if (slot < 2048) skey[slot] = k;
    }
  }
  __syncthreads();
  for (int k2 = 2; k2 <= 2048; k2 <<= 1) {
    for (int j = k2 >> 1; j > 0; j >>= 1) {
      #pragma unroll
      for (int e = 0; e < 2; ++e) {
        int idx = tid + e * 1024;
        int ixj = idx ^ j;
        if (ixj > idx) {
          unsigned long long a = skey[idx], bb = skey[ixj];
          bool sw = ((idx & k2) == 0) ? (a < bb) : (a > bb);
          if (sw) { skey[idx] = bb; skey[ixj] = a; }
        }
      }
      __syncthreads();
    }
  }
  if (tid < PRE_K) {
    unsigned long long k = skey[tid];
    unsigned idx = 0xFFFFFFFFu - (unsigned)(k & 0xFFFFFFFFu);
    float sc = __uint_as_float((unsigned)(k >> 32));
    size_t src = (size_t)n * P_TOT + idx;
    size_t dst = (size_t)n * PRE_K + tid;
    tscores[dst] = sc;
    tlabels[dst] = labels[src];
    *reinterpret_cast<float4*>(tboxes + 4 * dst) =
        *reinterpret_cast<const float4*>(boxes + 4 * src);
  }
}

// COLUMN-major suppression on a 2048-block grid (full-chip parallel).
// Divide-free guard-band; decisions bit-identical to fl(inter/denom)>0.6f.
__global__ __launch_bounds__(128) void iou_kernel(
    const float* __restrict__ tboxes, const int* __restrict__ tlabels,
    unsigned long long* __restrict__ colsupp)
{
  int jb = blockIdx.x, w = blockIdx.y, n = blockIdx.z;
  int tid = threadIdx.x;
  int j = jb * 128 + tid;
  bool jvalid = (j < PRE_K);
  int ibase = w * 64;

  if (ibase >= jb * 128 + 128) {
    if (jvalid) colsupp[((size_t)n * PRE_K + j) * 16 + w] = 0ULL;
    return;
  }

  __shared__ float4 sb[64];
  __shared__ float sa[64];
  if (tid < 64) {
    int i = ibase + tid;
    float4 v = make_float4(0.f, 0.f, 0.f, 0.f);
    if (i < PRE_K) {
      const float* b = tboxes + ((size_t)n * PRE_K + i) * 4;
      float offv = (float)tlabels[(size_t)n * PRE_K + i] * 4096.0f;
      v = make_float4(b[0] + offv, b[1] + offv, b[2] + offv, b[3] + offv);
    }
    sb[tid] = v;
    sa[tid] = (v.z - v.x) * (v.w - v.y);
  }
  __syncthreads();

  float4 bj = make_float4(0.f, 0.f, 0.f, 0.f);
  if (jvalid) {
    const float* b = tboxes + ((size_t)n * PRE_K + j) * 4;
    float offv = (float)tlabels[(size_t)n * PRE_K + j] * 4096.0f;
    bj = make_float4(b[0] + offv, b[1] + offv, b[2] + offv, b[3] + offv);
  }
  float aj = (bj.z - bj.x) * (bj.w - bj.y);

  unsigned long long m = 0, mb = 0;
  #pragma unroll
  for (int b = 0; b < 64; ++b) {
    float4 bi = sb[b];
    float ai = sa[b];
    float lx = fmaxf(bi.x, bj.x), ly = fmaxf(bi.y, bj.y);
    float rx = fminf(bi.z, bj.z), ry = fminf(bi.w, bj.w);
    float iw = fmaxf(rx - lx, 0.f), ih = fmaxf(ry - ly, 0.f);
    float inter = iw * ih;
    float denom = ai + aj - inter + 1e-9f;
    float t = inter - 0.6f * denom;
    if (t > 0.f) m |= (1ull << b);
    if (fabsf(t) <= denom * 7.62939453125e-6f) mb |= (1ull << b);  // 2^-17
  }
  if (mb) {
    unsigned long long r = mb;
    while (r) {
      int b = __ffsll(r) - 1; r &= r - 1;
      float4 bi = sb[b];
      float ai = sa[b];
      float lx = fmaxf(bi.x, bj.x), ly = fmaxf(bi.y, bj.y);
      float rx = fminf(bi.z, bj.z), ry = fminf(bi.w, bj.w);
      float iw = fmaxf(rx - lx, 0.f), ih = fmaxf(ry - ly, 0.f);
      float inter = iw * ih;
      float denom = ai + aj - inter + 1e-9f;
      float iou = inter / denom;
      if (iou > 0.6f) m |= (1ull << b); else m &= ~(1ull << b);
    }
  }
  unsigned long long tri;
  if (ibase >= j) tri = 0ULL;
  else if (j - ibase >= 64) tri = ~0ULL;
  else tri = (1ull << (j - ibase)) - 1ull;
  m &= tri;
  if (jvalid) colsupp[((size_t)n * PRE_K + j) * 16 + w] = m;
}

// Fused greedy + finalize. The suppression lower-triangle (136 chunk-words x
// 64 lanes = 69.6 KB) is cooperatively preloaded into LDS by ALL 16 waves
// (thread (w,l) copies the contiguous words c=0..w of its column j=w*64+l),
// so wave 0's fixpoint reads ds_read_b64 on demand -> NO register arrays,
// NO scratch spills (the round-14 greedyfin spilled X[16]+diag[16] at
// VGPR_Count=64 -> 135us serial scratch chain).
__global__ __launch_bounds__(1024) void greedyfin_kernel(
    const unsigned long long* __restrict__ colsupp, const float* __restrict__ tscores,
    const float* __restrict__ tboxes, const int* __restrict__ tlabels,
    float* __restrict__ out)
{
  int n = blockIdx.x;
  int tid = threadIdx.x;
  int wave = tid >> 6;
  int lane = tid & 63;
  __shared__ unsigned long long T[136 * 64];   // tri(c<=w): T[(w*(w+1)/2+c)*64+l]
  __shared__ unsigned long long keptw[16];

  {
    int wq = wave;          // 0..15
    int j = wq * 64 + lane;
    int base = (wq * (wq + 1)) / 2;
    if (j < PRE_K) {
      const unsigned long long* C = colsupp + ((size_t)n * PRE_K + j) * 16;
      for (int c = 0; c <= wq; ++c) T[(base + c) * 64 + lane] = C[c];
    } else {
      for (int c = 0; c <= wq; ++c) T[(base + c) * 64 + lane] = 0ULL;
    }
  }
  __syncthreads();

  if (wave == 0) {
    const float* sc = tscores + (size_t)n * PRE_K;
    float sval[16];
    #pragma unroll
    for (int k = 0; k < 16; ++k) {
      int j = k * 64 + lane;
      sval[k] = (j < PRE_K) ? sc[j] : 0.f;
    }
    unsigned removedbits = 0;
    #pragma unroll
    for (int c = 0; c < 16; ++c) {
      unsigned long long col = T[((c * (c + 1)) / 2 + c) * 64 + lane];
      unsigned long long sp = __ballot(sval[c] > 0.f);
      unsigned long long inc = __ballot(((removedbits >> c) & 1u) != 0u);
      unsigned long long K = sp & ~inc;
      unsigned long long kept = 0;
      for (int it = 0; it < 64; ++it) {
        unsigned long long Bsupp = __ballot((col & K) != 0ULL);
        unsigned long long Snew = K & ~Bsupp & ~kept;
        if (Snew == 0ULL) break;
        kept |= Snew;
        unsigned long long Bd = __ballot((col & kept) != 0ULL);
        K &= ~Bd;
      }
      if ((col & kept) != 0ULL) removedbits |= (1u << c);
      #pragma unroll
      for (int w = 0; w < 16; ++w) {
        if (w > c) {
          unsigned long long xw = T[((w * (w + 1)) / 2 + c) * 64 + lane];
          if ((xw & kept) != 0ULL) removedbits |= (1u << w);
        }
      }
      if (lane == 0) keptw[c] = kept;
    }
  }
  __syncthreads();

  __shared__ unsigned sk[1024];
  __shared__ unsigned sz[1024];
  bool inr = (tid < PRE_K);
  bool keep = inr && (((keptw[tid >> 6] >> (tid & 63)) & 1ull) != 0ull);
  sk[tid] = keep ? 1u : 0u;
  sz[tid] = (inr && !keep) ? 1u : 0u;
  __syncthreads();
  for (int ofs = 1; ofs < 1024; ofs <<= 1) {
    unsigned a = (tid >= ofs) ? sk[tid - ofs] : 0;
    unsigned b = (tid >= ofs) ? sz[tid - ofs] : 0;
    __syncthreads();
    sk[tid] += a; sz[tid] += b;
    __syncthreads();
  }
  int nk = (int)sk[1023];
  int slot = -1;
  if (inr) {
    if (keep) {
      int r = (int)sk[tid] - 1;
      if (r < POST_K) slot = r;
    } else {
      int r = nk + (int)sz[tid] - 1;
      if (r < POST_K) slot = r;
    }
  }
  if (slot >= 0) {
    size_t src = (size_t)n * PRE_K + tid;
    size_t ob = ((size_t)n * POST_K + slot) * 4;
    out[ob+0] = tboxes[4*src+0];
    out[ob+1] = tboxes[4*src+1];
    out[ob+2] = tboxes[4*src+2];
    out[ob+3] = tboxes[4*src+3];
    out[(size_t)NB*POST_K*4 + (size_t)n*POST_K + slot] = keep ? tscores[src] : 0.0f;
    out[(size_t)NB*POST_K*5 + (size_t)n*POST_K + slot] = (float)tlabels[src];
  }
}

extern "C" void kernel_launch(void* const* d_in, const int* in_sizes, int n_in,
                              void* d_out, int out_size, void* d_ws, size_t ws_size,
                              hipStream_t stream) {
  char* w = (char*)d_ws;
  auto carve = [&](size_t bytes) { char* p = w; w += (bytes + 255) & ~(size_t)255; return p; };
  int* labels   = (int*)carve((size_t)NB * P_TOT * 4);
  float* boxes  = (float*)carve((size_t)NB * P_TOT * 16);
  unsigned long long* keys = (unsigned long long*)carve((size_t)NB * P_TOT * 8);
  unsigned long long* colsupp = (unsigned long long*)carve((size_t)NB * PRE_K * 16 * 8);
  float* tboxes  = (float*)carve((size_t)NB * PRE_K * 16);
  float* tscores = (float*)carve((size_t)NB * PRE_K * 4);
  int* tlabels   = (int*)carve((size_t)NB * PRE_K * 4);

  const float* cls0 = (const float*)d_in[0];
  const float* reg0 = (const float*)d_in[1];
  const float* ctr0 = (const float*)d_in[2];
  const float* cls1 = (const float*)d_in[3];
  const float* reg1 = (const float*)d_in[4];
  const float* ctr1 = (const float*)d_in[5];
  const float* cls2 = (const float*)d_in[6];
  const float* reg2 = (const float*)d_in[7];
  const float* ctr2 = (const float*)d_in[8];
  const float* cls3 = (const float*)d_in[9];
  const float* reg3 = (const float*)d_in[10];
  const float* ctr3 = (const float*)d_in[11];
  const float* cls4 = (const float*)d_in[12];
  const float* reg4 = (const float*)d_in[13];
  const float* ctr4 = (const float*)d_in[14];

  dim3 dg((P4 + 63) / 64, NB);
  decode_kernel<<<dg, 256, 0, stream>>>(cls0, reg0, ctr0, cls1, reg1, ctr1,
                                        cls2, reg2, ctr2, cls3, reg3, ctr3,
                                        cls4, reg4, ctr4,
                                        labels, boxes, keys);
  topgather_kernel<<<NB, 1024, 0, stream>>>(keys, boxes, labels,
                                            tboxes, tscores, tlabels);
  dim3 gi(8, 16, NB);
  iou_kernel<<<gi, 128, 0, stream>>>(tboxes, tlabels, colsupp);
  greedyfin_kernel<<<NB, 1024, 0, stream>>>(colsupp, tscores, tboxes, tlabels, (float*)d_out);
}

// Round 16
// 67.422 us; speedup vs baseline: 4.6037x; 1.2318x over previous
//
#include <hip/hip_runtime.h>
#include <stdint.h>

#pragma clang fp contract(off)

#define NB 16
#define NC 80
#define P_TOT 17064
#define P4 (P_TOT / 4)
#define PRE_K 1000
#define POST_K 100

__device__ __forceinline__ float sigmoidf_(float x) {
  return 1.0f / (1.0f + expf(-x));
}

// Decode (monotonicity trick: argmax over classes == argmax over raw logits;
// exact score computed once for the winner). 20 class loads batched into
// registers; after the quad-reduce each lane decodes its OWN location.
__global__ __launch_bounds__(256, 2) void decode_kernel(
    const float* __restrict__ cls0, const float* __restrict__ reg0, const float* __restrict__ ctr0,
    const float* __restrict__ cls1, const float* __restrict__ reg1, const float* __restrict__ ctr1,
    const float* __restrict__ cls2, const float* __restrict__ reg2, const float* __restrict__ ctr2,
    const float* __restrict__ cls3, const float* __restrict__ reg3, const float* __restrict__ ctr3,
    const float* __restrict__ cls4, const float* __restrict__ reg4, const float* __restrict__ ctr4,
    int* __restrict__ labels, float* __restrict__ boxes,
    unsigned long long* __restrict__ keys)
{
  int quad = blockIdx.x * 64 + (threadIdx.x >> 2);
  int t4 = threadIdx.x & 3;
  int n = blockIdx.y;
  if (quad >= P4) return;
  int p0 = quad * 4;
  int off, wsh, hw; float stride; const float *cls, *reg, *ctr;
  if (p0 < 12800)      { off = 0;     wsh = 7; hw = 12800; stride = 8.f;   cls = cls0; reg = reg0; ctr = ctr0; }
  else if (p0 < 16000) { off = 12800; wsh = 6; hw = 3200;  stride = 16.f;  cls = cls1; reg = reg1; ctr = ctr1; }
  else if (p0 < 16800) { off = 16000; wsh = 5; hw = 800;   stride = 32.f;  cls = cls2; reg = reg2; ctr = ctr2; }
  else if (p0 < 17008) { off = 16800; wsh = 4; hw = 208;   stride = 64.f;  cls = cls3; reg = reg3; ctr = ctr3; }
  else                 { off = 17008; wsh = 3; hw = 56;    stride = 128.f; cls = cls4; reg = reg4; ctr = ctr4; }
  int loc0 = p0 - off;
  int y = loc0 >> wsh;
  int x0 = loc0 & ((1 << wsh) - 1);
  float py = (float)y * stride + 0.5f * stride;

  int c0 = t4 * 20;
  const float* cptr = cls + (size_t)n * NC * hw + (size_t)c0 * hw + loc0;
  float4 cv[20];
  #pragma unroll
  for (int k = 0; k < 20; ++k)
    cv[k] = *reinterpret_cast<const float4*>(cptr + (size_t)k * hw);

  float best[4] = { -3.4e38f, -3.4e38f, -3.4e38f, -3.4e38f };
  int bl[4] = { c0, c0, c0, c0 };
  #pragma unroll
  for (int k = 0; k < 20; ++k) {
    int c = c0 + k;
    if (cv[k].x > best[0]) { best[0] = cv[k].x; bl[0] = c; }
    if (cv[k].y > best[1]) { best[1] = cv[k].y; bl[1] = c; }
    if (cv[k].z > best[2]) { best[2] = cv[k].z; bl[2] = c; }
    if (cv[k].w > best[3]) { best[3] = cv[k].w; bl[3] = c; }
  }
  #pragma unroll
  for (int e = 0; e < 4; ++e) {
    #pragma unroll
    for (int d = 1; d <= 2; d <<= 1) {
      float ob = __shfl_xor(best[e], d);
      int ol = __shfl_xor(bl[e], d);
      if (ob > best[e] || (ob == best[e] && ol < bl[e])) { best[e] = ob; bl[e] = ol; }
    }
  }

  int e = t4;
  int loce = loc0 + e;
  float sctr_e = sigmoidf_(ctr[(size_t)n * hw + loce]);
  const float* rbase = reg + (size_t)n * 4 * hw + loce;
  float dl = rbase[0];
  float dt = rbase[(size_t)hw];
  float dr = rbase[(size_t)2 * hw];
  float db = rbase[(size_t)3 * hw];

  float s = sqrtf(sigmoidf_(best[e]) * sctr_e);
  float val = (s > 0.05f) ? s : 0.0f;
  float px = (float)(x0 + e) * stride + 0.5f * stride;
  float x1 = fminf(fmaxf(px - dl, 0.f), 1024.f);
  float y1 = fminf(fmaxf(py - dt, 0.f), 800.f);
  float x2 = fminf(fmaxf(px + dr, 0.f), 1024.f);
  float y2 = fminf(fmaxf(py + db, 0.f), 800.f);

  size_t o = (size_t)n * P_TOT + p0 + e;
  labels[o] = bl[e];
  *reinterpret_cast<float4*>(boxes + 4 * o) = make_float4(x1, y1, x2, y2);
  keys[o] = ((unsigned long long)__float_as_uint(val) << 32)
          | (unsigned long long)(0xFFFFFFFFu - (unsigned)(p0 + e));
}

// Fully-fused top-k, SORT-FREE. One block per batch.
// Scores in [0,1] -> key>>48 < 0x4000 -> 16384-bin u32 LDS hist.
// Pass 1: histogram. Two-level shfl suffix scan -> dsel (3 barriers, not 20).
// Bins >= dsel rewritten hist[h] = base<<16 (base < 2048). Pass 2: scatter;
// atomicAdd(+1) counts arrivals in low 16 bits -> slot = base + arrival
// (identical slot semantics + <2048 guard as before). Segments [base,
// base+cnt) tile [0,M) in descending-bin order; keys unique, so the global
// sorted position of key k in bin h is base_h + |{q in seg : skey[q] > k}|.
// Rank each slot in parallel and gather directly -> NO bitonic sort.
__global__ __launch_bounds__(1024) void topgather_kernel(
    const unsigned long long* __restrict__ keys,
    const float* __restrict__ boxes, const int* __restrict__ labels,
    float* __restrict__ tboxes, float* __restrict__ tscores, int* __restrict__ tlabels)
{
  int n = blockIdx.x;
  int tid = threadIdx.x;
  int wave = tid >> 6;
  int lane = tid & 63;
  __shared__ unsigned hist[16384];
  __shared__ unsigned Wt[16], Wsuf[16];
  __shared__ unsigned s_d, s_M;
  __shared__ unsigned long long skey[2048];

  for (int i = tid; i < 16384; i += 1024) hist[i] = 0;
  __syncthreads();
  const unsigned long long* bk = keys + (size_t)n * P_TOT;
  for (int p = tid; p < P_TOT; p += 1024) {
    unsigned h = (unsigned)(bk[p] >> 48);   // < 16384 guaranteed
    atomicAdd(&hist[h], 1u);
  }
  __syncthreads();

  // strip sums (16 bins/thread, registers)
  unsigned bvs[16];
  unsigned ssum = 0;
  #pragma unroll
  for (int q = 0; q < 16; ++q) { bvs[q] = hist[tid * 16 + q]; ssum += bvs[q]; }
  // wave-level inclusive suffix scan of ssum
  unsigned v = ssum;
  #pragma unroll
  for (int d = 1; d < 64; d <<= 1) {
    unsigned t = __shfl_down(v, d);
    if (lane + d < 64) v += t;
  }
  if (lane == 0) Wt[wave] = v;   // wave total
  __syncthreads();
  if (wave == 0 && lane < 16) {
    unsigned wv = Wt[lane];
    unsigned own = wv;
    #pragma unroll
    for (int d = 1; d < 16; d <<= 1) {
      unsigned t = __shfl_down(wv, d);
      if (lane + d < 16) wv += t;
    }
    Wsuf[lane] = wv - own;       // exclusive suffix over waves
  }
  __syncthreads();
  unsigned At = v + Wsuf[wave];  // strips tid..1023
  unsigned An = At - ssum;       // strips tid+1..1023
  {
    if (At >= PRE_K && An < PRE_K) {   // unique crossing strip (monotone)
      unsigned cum = An;
      int d = tid * 16;
      unsigned M = 0;
      bool done = false;
      #pragma unroll
      for (int b = 15; b >= 0; --b) {
        if (!done) {
          cum += bvs[b];
          if (cum >= PRE_K) { d = tid * 16 + b; M = cum; done = true; }
        }
      }
      s_d = (unsigned)d;
      s_M = M;                   // total candidates = suffix count at dsel
    }
  }
  __syncthreads();
  unsigned dsel = s_d;
  // rewrite bins >= dsel: hist[h] = base<<16 (low 16 = arrival counter)
  {
    unsigned cum = An;
    #pragma unroll
    for (int b = 15; b >= 0; --b) {
      unsigned h = (unsigned)(tid * 16 + b);
      if (h >= dsel) hist[h] = cum << 16;
      cum += bvs[b];
    }
  }
  __syncthreads();
  // pass 2: scatter candidates (slot = base + arrival, guard < 2048)
  for (int p = tid; p < P_TOT; p += 1024) {
    unsigned long long k = bk[p];
    unsigned h = (unsigned)(k >> 48);
    if (h >= dsel) {
      unsigned old = atomicAdd(&hist[h], 1u);
      unsigned slot = (old >> 16) + (old & 0xFFFFu);
      if (slot < 2048) skey[slot] = k;
    }
  }
  __syncthreads();
  // rank within bin segment + direct gather
  unsigned Mcap = s_M < 2048u ? s_M : 2048u;
  #pragma unroll
  for (int e = 0; e < 2; ++e) {
    unsigned sidx = (unsigned)tid + e * 1024;
    if (sidx < Mcap) {
      unsigned long long k = skey[sidx];
      unsigned h = (unsigned)(k >> 48);
      unsigned info = hist[h];
      unsigned start = info >> 16;
      unsigned end = start + (info & 0xFFFFu);
      if (end > 2048u) end = 2048u;
      unsigned rank = 0;
      for (unsigned q = start; q < end; ++q)
        rank += (skey[q] > k) ? 1u : 0u;
      unsigned pos = start + rank;
      if (pos < PRE_K) {
        unsigned idx = 0xFFFFFFFFu - (unsigned)(k & 0xFFFFFFFFu);
        float sc = __uint_as_float((unsigned)(k >> 32));
        size_t src = (size_t)n * P_TOT + idx;
        size_t dst = (size_t)n * PRE_K + pos;
        tscores[dst] = sc;
        tlabels[dst] = labels[src];
        *reinterpret_cast<float4*>(tboxes + 4 * dst) =
            *reinterpret_cast<const float4*>(boxes + 4 * src);
      }
    }
  }
}

// COLUMN-major suppression on a 2048-block grid (full-chip parallel).
// Divide-free guard-band; decisions bit-identical to fl(inter/denom)>0.6f.
__global__ __launch_bounds__(128) void iou_kernel(
    const float* __restrict__ tboxes, const int* __restrict__ tlabels,
    unsigned long long* __restrict__ colsupp)
{
  int jb = blockIdx.x, w = blockIdx.y, n = blockIdx.z;
  int tid = threadIdx.x;
  int j = jb * 128 + tid;
  bool jvalid = (j < PRE_K);
  int ibase = w * 64;

  if (ibase >= jb * 128 + 128) {
    if (jvalid) colsupp[((size_t)n * PRE_K + j) * 16 + w] = 0ULL;
    return;
  }

  __shared__ float4 sb[64];
  __shared__ float sa[64];
  if (tid < 64) {
    int i = ibase + tid;
    float4 v = make_float4(0.f, 0.f, 0.f, 0.f);
    if (i < PRE_K) {
      const float* b = tboxes + ((size_t)n * PRE_K + i) * 4;
      float offv = (float)tlabels[(size_t)n * PRE_K + i] * 4096.0f;
      v = make_float4(b[0] + offv, b[1] + offv, b[2] + offv, b[3] + offv);
    }
    sb[tid] = v;
    sa[tid] = (v.z - v.x) * (v.w - v.y);
  }
  __syncthreads();

  float4 bj = make_float4(0.f, 0.f, 0.f, 0.f);
  if (jvalid) {
    const float* b = tboxes + ((size_t)n * PRE_K + j) * 4;
    float offv = (float)tlabels[(size_t)n * PRE_K + j] * 4096.0f;
    bj = make_float4(b[0] + offv, b[1] + offv, b[2] + offv, b[3] + offv);
  }
  float aj = (bj.z - bj.x) * (bj.w - bj.y);

  unsigned long long m = 0, mb = 0;
  #pragma unroll
  for (int b = 0; b < 64; ++b) {
    float4 bi = sb[b];
    float ai = sa[b];
    float lx = fmaxf(bi.x, bj.x), ly = fmaxf(bi.y, bj.y);
    float rx = fminf(bi.z, bj.z), ry = fminf(bi.w, bj.w);
    float iw = fmaxf(rx - lx, 0.f), ih = fmaxf(ry - ly, 0.f);
    float inter = iw * ih;
    float denom = ai + aj - inter + 1e-9f;
    float t = inter - 0.6f * denom;
    if (t > 0.f) m |= (1ull << b);
    if (fabsf(t) <= denom * 7.62939453125e-6f) mb |= (1ull << b);  // 2^-17
  }
  if (mb) {
    unsigned long long r = mb;
    while (r) {
      int b = __ffsll(r) - 1; r &= r - 1;
      float4 bi = sb[b];
      float ai = sa[b];
      float lx = fmaxf(bi.x, bj.x), ly = fmaxf(bi.y, bj.y);
      float rx = fminf(bi.z, bj.z), ry = fminf(bi.w, bj.w);
      float iw = fmaxf(rx - lx, 0.f), ih = fmaxf(ry - ly, 0.f);
      float inter = iw * ih;
      float denom = ai + aj - inter + 1e-9f;
      float iou = inter / denom;
      if (iou > 0.6f) m |= (1ull << b); else m &= ~(1ull << b);
    }
  }
  unsigned long long tri;
  if (ibase >= j) tri = 0ULL;
  else if (j - ibase >= 64) tri = ~0ULL;
  else tri = (1ull << (j - ibase)) - 1ull;
  m &= tri;
  if (jvalid) colsupp[((size_t)n * PRE_K + j) * 16 + w] = m;
}

// Fused greedy + finalize with LDS-staged suppression triangle (no spills).
__global__ __launch_bounds__(1024) void greedyfin_kernel(
    const unsigned long long* __restrict__ colsupp, const float* __restrict__ tscores,
    const float* __restrict__ tboxes, const int* __restrict__ tlabels,
    float* __restrict__ out)
{
  int n = blockIdx.x;
  int tid = threadIdx.x;
  int wave = tid >> 6;
  int lane = tid & 63;
  __shared__ unsigned long long T[136 * 64];   // tri(c<=w): T[(w*(w+1)/2+c)*64+l]
  __shared__ unsigned long long keptw[16];

  {
    int wq = wave;
    int j = wq * 64 + lane;
    int base = (wq * (wq + 1)) / 2;
    if (j < PRE_K) {
      const unsigned long long* C = colsupp + ((size_t)n * PRE_K + j) * 16;
      for (int c = 0; c <= wq; ++c) T[(base + c) * 64 + lane] = C[c];
    } else {
      for (int c = 0; c <= wq; ++c) T[(base + c) * 64 + lane] = 0ULL;
    }
  }
  __syncthreads();

  if (wave == 0) {
    const float* sc = tscores + (size_t)n * PRE_K;
    float sval[16];
    #pragma unroll
    for (int k = 0; k < 16; ++k) {
      int j = k * 64 + lane;
      sval[k] = (j < PRE_K) ? sc[j] : 0.f;
    }
    unsigned removedbits = 0;
    #pragma unroll
    for (int c = 0; c < 16; ++c) {
      unsigned long long col = T[((c * (c + 1)) / 2 + c) * 64 + lane];
      unsigned long long sp = __ballot(sval[c] > 0.f);
      unsigned long long inc = __ballot(((removedbits >> c) & 1u) != 0u);
      unsigned long long K = sp & ~inc;
      unsigned long long kept = 0;
      for (int it = 0; it < 64; ++it) {
        unsigned long long Bsupp = __ballot((col & K) != 0ULL);
        unsigned long long Snew = K & ~Bsupp & ~kept;
        if (Snew == 0ULL) break;
        kept |= Snew;
        unsigned long long Bd = __ballot((col & kept) != 0ULL);
        K &= ~Bd;
      }
      if ((col & kept) != 0ULL) removedbits |= (1u << c);
      #pragma unroll
      for (int w = 0; w < 16; ++w) {
        if (w > c) {
          unsigned long long xw = T[((w * (w + 1)) / 2 + c) * 64 + lane];
          if ((xw & kept) != 0ULL) removedbits |= (1u << w);
        }
      }
      if (lane == 0) keptw[c] = kept;
    }
  }
  __syncthreads();

  __shared__ unsigned sk[1024];
  __shared__ unsigned sz[1024];
  bool inr = (tid < PRE_K);
  bool keep = inr && (((keptw[tid >> 6] >> (tid & 63)) & 1ull) != 0ull);
  sk[tid] = keep ? 1u : 0u;
  sz[tid] = (inr && !keep) ? 1u : 0u;
  __syncthreads();
  for (int ofs = 1; ofs < 1024; ofs <<= 1) {
    unsigned a = (tid >= ofs) ? sk[tid - ofs] : 0;
    unsigned b = (tid >= ofs) ? sz[tid - ofs] : 0;
    __syncthreads();
    sk[tid] += a; sz[tid] += b;
    __syncthreads();
  }
  int nk = (int)sk[1023];
  int slot = -1;
  if (inr) {
    if (keep) {
      int r = (int)sk[tid] - 1;
      if (r < POST_K) slot = r;
    } else {
      int r = nk + (int)sz[tid] - 1;
      if (r < POST_K) slot = r;
    }
  }
  if (slot >= 0) {
    size_t src = (size_t)n * PRE_K + tid;
    size_t ob = ((size_t)n * POST_K + slot) * 4;
    out[ob+0] = tboxes[4*src+0];
    out[ob+1] = tboxes[4*src+1];
    out[ob+2] = tboxes[4*src+2];
    out[ob+3] = tboxes[4*src+3];
    out[(size_t)NB*POST_K*4 + (size_t)n*POST_K + slot] = keep ? tscores[src] : 0.0f;
    out[(size_t)NB*POST_K*5 + (size_t)n*POST_K + slot] = (float)tlabels[src];
  }
}

extern "C" void kernel_launch(void* const* d_in, const int* in_sizes, int n_in,
                              void* d_out, int out_size, void* d_ws, size_t ws_size,
                              hipStream_t stream) {
  char* w = (char*)d_ws;
  auto carve = [&](size_t bytes) { char* p = w; w += (bytes + 255) & ~(size_t)255; return p; };
  int* labels   = (int*)carve((size_t)NB * P_TOT * 4);
  float* boxes  = (float*)carve((size_t)NB * P_TOT * 16);
  unsigned long long* keys = (unsigned long long*)carve((size_t)NB * P_TOT * 8);
  unsigned long long* colsupp = (unsigned long long*)carve((size_t)NB * PRE_K * 16 * 8);
  float* tboxes  = (float*)carve((size_t)NB * PRE_K * 16);
  float* tscores = (float*)carve((size_t)NB * PRE_K * 4);
  int* tlabels   = (int*)carve((size_t)NB * PRE_K * 4);

  const float* cls0 = (const float*)d_in[0];
  const float* reg0 = (const float*)d_in[1];
  const float* ctr0 = (const float*)d_in[2];
  const float* cls1 = (const float*)d_in[3];
  const float* reg1 = (const float*)d_in[4];
  const float* ctr1 = (const float*)d_in[5];
  const float* cls2 = (const float*)d_in[6];
  const float* reg2 = (const float*)d_in[7];
  const float* ctr2 = (const float*)d_in[8];
  const float* cls3 = (const float*)d_in[9];
  const float* reg3 = (const float*)d_in[10];
  const float* ctr3 = (const float*)d_in[11];
  const float* cls4 = (const float*)d_in[12];
  const float* reg4 = (const float*)d_in[13];
  const float* ctr4 = (const float*)d_in[14];

  dim3 dg((P4 + 63) / 64, NB);
  decode_kernel<<<dg, 256, 0, stream>>>(cls0, reg0, ctr0, cls1, reg1, ctr1,
                                        cls2, reg2, ctr2, cls3, reg3, ctr3,
                                        cls4, reg4, ctr4,
                                        labels, boxes, keys);
  topgather_kernel<<<NB, 1024, 0, stream>>>(keys, boxes, labels,
                                            tboxes, tscores, tlabels);
  dim3 gi(8, 16, NB);
  iou_kernel<<<gi, 128, 0, stream>>>(tboxes, tlabels, colsupp);
  greedyfin_kernel<<<NB, 1024, 0, stream>>>(colsupp, tscores, tboxes, tlabels, (float*)d_out);
}